// Round 4
// baseline (151.488 us; speedup 1.0000x reference)
//
#include <hip/hip_runtime.h>
#include <math.h>

// R4: 32 blocks x 1024 threads — ONE block per batch element n.
// Theory: bottom-up phase model accounts for only ~13 of 43.7 µs; the rest is
// grid-scaling overhead (launching 192 16-wave/90KB-LDS workgroups ≈ 3072
// waves). Collapsing to 32 blocks (512 waves) removes it, plus:
//  - conv1 no longer 6x redundant; BN1 stats same code, now all blocks.
//  - conv2: each thread owns px=t&255 and a 6-channel co-group (t>>8)*6,
//    accumulating over ALL 24 input channels. LDS read count per thread is
//    unchanged vs R1 (reads depend only on ci coverage); FMAs grow ~6x but
//    stay ~5 µs issue-bound. No cross-slot LDS reduce needed at all.
//  - BN2 stats + ssum entirely in-block: flags3/flags4/pairs rounds DELETED.
//    Only the two algorithmically-forced global barriers remain (BN1, BN2),
//    32 flags each, relaxed polls (R2), release-stored MAGIC (unchanged).
//  - tail: R2's fused fc1 (coef = qfull + 256*sterm), float4 mg-split; the
//    17.4KB reduce buffer is ALIASED over y1u (dead after conv2).
// LDS ~74 KB. ws is 0xAA-poisoned before every call -> flags start != MAGIC.
//
// Carried: R1 conv2 LDS layout (bordered pitch-40 bf16 tile, b32 pair reads,
// 2-way-free bank geometry), R2 relaxed polls + L2 prefetch fillers + fused
// fc1 tail, R3's all-of-w_rel prefetch.

#define MAGIC 0x13579BDFu
#define AGENT __HIP_MEMORY_SCOPE_AGENT
#define PITCH 40                 // ushorts per row (row 0 and col 0 are zero border)
#define NROWS 33                 // rows 0..32 (row = oh+1)
#define CHSZ (PITCH * NROWS)     // 1320 ushorts per channel plane
#define C_OUT 24

__device__ __forceinline__ float aload(const float* p) {
  return __hip_atomic_load(p, __ATOMIC_RELAXED, AGENT);
}
__device__ __forceinline__ void astore(float* p, float v) {
  __hip_atomic_store(p, v, __ATOMIC_RELAXED, AGENT);
}
__device__ __forceinline__ void waitflag(const unsigned* f) {
  while (__hip_atomic_load(f, __ATOMIC_RELAXED, AGENT) != MAGIC)
    __builtin_amdgcn_s_sleep(1);
}

__global__ __launch_bounds__(1024) void fused_kernel(
    const float* __restrict__ img, const float* __restrict__ ques,
    const float* __restrict__ c1w, const float* __restrict__ c1b,
    const float* __restrict__ g1,  const float* __restrict__ bt1,
    const float* __restrict__ c2w, const float* __restrict__ c2b,
    const float* __restrict__ g2,  const float* __restrict__ bt2,
    const float* __restrict__ w_rel, const float* __restrict__ b_rel,
    const float* __restrict__ w_fc1, const float* __restrict__ b_fc1,
    const float* __restrict__ w_fc2, const float* __restrict__ b_fc2,
    float* __restrict__ out,
    unsigned* __restrict__ flags1, unsigned* __restrict__ flags2,
    float* __restrict__ p1, float* __restrict__ p2) {
  const int t = threadIdx.x;
  const int n = blockIdx.x;               // 0..31: one block per batch element
  const int lane = t & 63, wid = t >> 6;

  __shared__ __align__(16) unsigned short y1u[24 * CHSZ];  // 63.4 KB
  __shared__ float s_a[C_OUT], s_b[C_OUT];    // BN1 scale/shift
  __shared__ float s_a2[C_OUT], s_b2[C_OUT];  // BN2 scale/shift (all 24 ch)
  __shared__ float chS[96], chS2[96];         // per-co x per-wave-subgroup partials
  __shared__ float qpart[1024];
  __shared__ float qfull[128];
  __shared__ float s_s[26];
  __shared__ float s_coef[128];

  float* red = (float*)y1u;   // fc1 reduce buffer, aliased after conv2 is done

  // zero the borders (row 0 fully; col 0 of rows 1..32) before first use
  if (t < 24 * PITCH) {
    int ch = t / PITCH;
    y1u[ch * CHSZ + (t - ch * PITCH)] = 0;            // row 0
  }
  if (t < 768)
    y1u[(t >> 5) * CHSZ + ((t & 31) + 1) * PITCH] = 0; // col 0, rows 1..32

  // ---------------- phase 1: conv1, 1 pixel/thread, all 24 co ----------------
  {
    int oh = t >> 5, ow = t & 31;
    float win[27];
    #pragma unroll
    for (int ci = 0; ci < 3; ci++)
      #pragma unroll
      for (int kh = 0; kh < 3; kh++) {
        int ih = oh * 2 - 1 + kh;
        #pragma unroll
        for (int kw = 0; kw < 3; kw++) {
          int iw = ow * 2 - 1 + kw;
          win[ci * 9 + kh * 3 + kw] =
              (ih >= 0 && iw >= 0) ? img[(n * 3 + ci) * 4096 + ih * 64 + iw] : 0.f;
        }
      }
    #pragma unroll
    for (int co = 0; co < C_OUT; co++) {
      float acc = c1b[co];
      #pragma unroll
      for (int q = 0; q < 27; q++) acc += win[q] * c1w[co * 27 + q];
      unsigned bits = __float_as_uint(acc);
      unsigned rr = (bits + 0x7FFFu + ((bits >> 16) & 1u)) >> 16;  // rne
      y1u[co * CHSZ + (oh + 1) * PITCH + (ow + 1)] = (unsigned short)rr;
    }
  }
  __syncthreads();

  // ---------------- BN1 partial stats for this n (all 24 ch) ----------------
  if (t < 768) {
    int ch = t >> 5, l = t & 31;
    float s = 0.f, s2 = 0.f;
    #pragma unroll
    for (int i = 0; i < 32; i++) {
      float x = __uint_as_float(
          (unsigned)y1u[ch * CHSZ + (i + 1) * PITCH + (l + 1)] << 16);
      s += x; s2 += x * x;
    }
    #pragma unroll
    for (int off = 16; off > 0; off >>= 1) {
      s += __shfl_down(s, off, 32);
      s2 += __shfl_down(s2, off, 32);
    }
    if (l == 0) {
      astore(&p1[ch * 32 + n], s);
      astore(&p1[768 + ch * 32 + n], s2);
    }
  }
  __syncthreads();
  if (t == 0)
    __hip_atomic_store(&flags1[n], MAGIC, __ATOMIC_RELEASE, AGENT);

  // ---- L2 prefetch filler (fills the BN1-wait window) ----
  {
    float pf = 0.f;
    #pragma unroll
    for (int i = 0; i < 4; i++) pf += w_fc1[(t + i * 1024) * 32];  // all 4096 lines
    if (t < 720) pf += w_rel[t * 32];     // all of w_rel (180*128 floats)
    if (t < 64)  pf += w_fc2[t * 32];     // 8 KB
    if (t < 32)  pf += b_fc1[t * 32];     // 4 KB
    asm volatile("" :: "v"(pf));          // keep loads alive
  }

  // ---------------- wait BN1 stats + finalize ----------------
  if (t < 32) waitflag(&flags1[t]);
  __syncthreads();
  if (t < 768) {
    int ch = t >> 5, j = t & 31;
    float s = aload(&p1[ch * 32 + j]);
    float s2 = aload(&p1[768 + ch * 32 + j]);
    #pragma unroll
    for (int off = 16; off > 0; off >>= 1) {
      s += __shfl_down(s, off, 32);
      s2 += __shfl_down(s2, off, 32);
    }
    if (j == 0) {
      float mu = s * (1.f / 32768.f);
      float var = s2 * (1.f / 32768.f) - mu * mu;
      float a = rsqrtf(var + 1e-5f) * g1[ch];
      s_a[ch] = a;
      s_b[ch] = bt1[ch] - mu * a;
    }
  }
  __syncthreads();

  // ---------------- phase 2: conv2 — px = t&255, co-group (t>>8)*6 ----------
  const int px = t & 255;
  const int sgrp = t >> 8;                 // 0..3, wave-uniform
  const int cb = sgrp * 6;                 // this thread's 6 output channels
  float acc[6];
  {
    const int o2h = px >> 4, o2w = px & 15;
    #pragma unroll
    for (int j = 0; j < 6; j++) acc[j] = c2b[cb + j];
    for (int ci = 0; ci < 24; ci++) {
      const float a1 = s_a[ci], b1 = s_b[ci];
      const unsigned* chp = (const unsigned*)(y1u + ci * CHSZ);
      #pragma unroll
      for (int kh = 0; kh < 3; kh++) {
        const int row = o2h * 2 + kh;              // = ih+1, in 0..32
        const unsigned* pr = chp + row * (PITCH / 2);
        unsigned w0 = pr[o2w];                     // cols 2*o2w, 2*o2w+1
        unsigned w1 = pr[o2w + 1];                 // cols 2*o2w+2
        float x0 = __uint_as_float(w0 << 16);
        float x1 = __uint_as_float(w0 & 0xffff0000u);
        float x2 = __uint_as_float(w1 << 16);
        x0 = fmaxf(fmaf(x0, a1, b1), 0.f);
        x1 = fmaxf(fmaf(x1, a1, b1), 0.f);
        x2 = fmaxf(fmaf(x2, a1, b1), 0.f);
        if (row == 0) { x0 = 0.f; x1 = 0.f; x2 = 0.f; }  // top zero-pad
        if (o2w == 0) x0 = 0.f;                           // left zero-pad
        #pragma unroll
        for (int j = 0; j < 6; j++) {
          const float* wp = c2w + ((cb + j) * C_OUT + ci) * 9 + kh * 3;
          acc[j] = fmaf(x0, wp[0], fmaf(x1, wp[1], fmaf(x2, wp[2], acc[j])));
        }
      }
    }
  }

  // ---------------- BN2 partial stats for this n (in-block) ----------------
  {
    #pragma unroll
    for (int j = 0; j < 6; j++) {
      float s = acc[j], s2 = acc[j] * acc[j];
      #pragma unroll
      for (int off = 32; off > 0; off >>= 1) {
        s += __shfl_down(s, off, 64);
        s2 += __shfl_down(s2, off, 64);
      }
      if (lane == 0) {
        chS[(cb + j) * 4 + (wid & 3)] = s;
        chS2[(cb + j) * 4 + (wid & 3)] = s2;
      }
    }
  }
  __syncthreads();
  if (t < C_OUT) {
    float s = chS[t * 4] + chS[t * 4 + 1] + chS[t * 4 + 2] + chS[t * 4 + 3];
    float s2 = chS2[t * 4] + chS2[t * 4 + 1] + chS2[t * 4 + 2] + chS2[t * 4 + 3];
    astore(&p2[t * 32 + n], s);
    astore(&p2[768 + t * 32 + n], s2);
  }
  __syncthreads();
  if (t == 0)
    __hip_atomic_store(&flags2[n], MAGIC, __ATOMIC_RELEASE, AGENT);

  // ---- qfull filler (fills the BN2-wait window) ----
  {
    int m = t & 127, g = t >> 7;
    const float* qv = ques + n * 128;
    float q = 0.f;
    for (int k = g * 16; k < g * 16 + 16; k++)
      q += qv[k] * w_rel[(52 + k) * 128 + m];
    qpart[t] = q;
  }
  __syncthreads();
  if (t < 128) {
    float q = b_rel[t];
    #pragma unroll
    for (int g = 0; g < 8; g++) q += qpart[g * 128 + t];
    qfull[t] = 65536.f * q;
  }

  // ---------------- wait BN2 stats + finalize all 24 channels ----------------
  if (t < 32) waitflag(&flags2[t]);
  __syncthreads();
  if (t < 768) {
    int ch = t >> 5, j = t & 31;
    float s = aload(&p2[ch * 32 + j]);
    float s2 = aload(&p2[768 + ch * 32 + j]);
    #pragma unroll
    for (int off = 16; off > 0; off >>= 1) {
      s += __shfl_down(s, off, 32);
      s2 += __shfl_down(s2, off, 32);
    }
    if (j == 0) {
      float mu = s * (1.f / 8192.f);
      float var = s2 * (1.f / 8192.f) - mu * mu;
      float a = rsqrtf(var + 1e-5f) * g2[ch];
      s_a2[ch] = a;
      s_b2[ch] = bt2[ch] - mu * a;
    }
  }
  __syncthreads();

  // ---------------- relu(bn2) spatial sums -> s_s (in-block, no flags) ------
  {
    #pragma unroll
    for (int j = 0; j < 6; j++) {
      float v = acc[j] * s_a2[cb + j] + s_b2[cb + j];
      v = v > 0.f ? v : 0.f;
      #pragma unroll
      for (int off = 32; off > 0; off >>= 1) v += __shfl_down(v, off, 64);
      if (lane == 0) chS[(cb + j) * 4 + (wid & 3)] = v;
    }
  }
  __syncthreads();
  if (t < C_OUT)
    s_s[t] = chS[t * 4] + chS[t * 4 + 1] + chS[t * 4 + 2] + chS[t * 4 + 3];
  if (t == 24 || t == 25) {
    float cs = 0.f;
    for (int i = 0; i < 16; i++) cs += -1.f + 2.f * (float)i / 15.f;
    s_s[t] = 16.f * cs;
  }
  __syncthreads();

  // ---------------- tail: sterm + fused fc1 + fc2 ----------------
  // sterm partials across all 1024 threads: col = t&127, d-range by g = t>>7
  {
    int col = t & 127, g = t >> 7;
    float p = 0.f;
    #pragma unroll
    for (int dd = 0; dd < 4; dd++) {
      int d = g + dd * 8;
      if (d < 26)
        p += s_s[d] * (w_rel[d * 128 + col] + w_rel[(26 + d) * 128 + col]);
    }
    qpart[t] = p;
  }
  __syncthreads();
  if (t < 128) {
    float sterm = 0.f;
    #pragma unroll
    for (int g = 0; g < 8; g++) sterm += qpart[g * 128 + t];
    s_coef[t] = qfull[t] + 256.f * sterm;
  }
  __syncthreads();

  // fused fc1: coef @ w_fc1, float4 loads, mg-split; red aliases dead y1u
  {
    const int cg = t & 255, mg = t >> 8;          // cols 4cg..4cg+3, m mg*32..+31
    const float4* wp = (const float4*)(w_fc1) + mg * 32 * 256 + cg;
    float4 a4 = make_float4(0.f, 0.f, 0.f, 0.f);
    #pragma unroll 8
    for (int k = 0; k < 32; k++) {
      float c = s_coef[mg * 32 + k];
      float4 w = wp[k * 256];
      a4.x += c * w.x; a4.y += c * w.y; a4.z += c * w.z; a4.w += c * w.w;
    }
    red[cg * 17 + mg * 4 + 0] = a4.x;
    red[cg * 17 + mg * 4 + 1] = a4.y;
    red[cg * 17 + mg * 4 + 2] = a4.z;
    red[cg * 17 + mg * 4 + 3] = a4.w;
  }
  __syncthreads();
  float a0, a1v;
  {
    float h = b_fc1[t];
    #pragma unroll
    for (int mg = 0; mg < 4; mg++) h += red[(t >> 2) * 17 + mg * 4 + (t & 3)];
    h = h > 0.f ? h : 0.f;
    a0 = h * w_fc2[2 * t];
    a1v = h * w_fc2[2 * t + 1];
  }
  __syncthreads();
  {
    #pragma unroll
    for (int off = 32; off > 0; off >>= 1) {
      a0 += __shfl_down(a0, off, 64);
      a1v += __shfl_down(a1v, off, 64);
    }
    if (lane == 0) { chS[wid] = a0; chS2[wid] = a1v; }
  }
  __syncthreads();
  if (t == 0) {
    float b0 = 0.f, b1 = 0.f;
    #pragma unroll
    for (int i = 0; i < 16; i++) { b0 += chS[i]; b1 += chS2[i]; }
    out[n * 2 + 0] = b0 + b_fc2[0];
    out[n * 2 + 1] = b1 + b_fc2[1];
  }
}

extern "C" void kernel_launch(void* const* d_in, const int* in_sizes, int n_in,
                              void* d_out, int out_size, void* d_ws, size_t ws_size,
                              hipStream_t stream) {
  const float* image   = (const float*)d_in[0];
  const float* ques    = (const float*)d_in[1];
  const float* conv1_w = (const float*)d_in[2];
  const float* conv1_b = (const float*)d_in[3];
  const float* bn1_g   = (const float*)d_in[4];
  const float* bn1_b   = (const float*)d_in[5];
  const float* conv2_w = (const float*)d_in[6];
  const float* conv2_b = (const float*)d_in[7];
  const float* bn2_g   = (const float*)d_in[8];
  const float* bn2_b   = (const float*)d_in[9];
  const float* w_rel   = (const float*)d_in[10];
  const float* b_rel   = (const float*)d_in[11];
  const float* w_fc1   = (const float*)d_in[12];
  const float* b_fc1   = (const float*)d_in[13];
  const float* w_fc2   = (const float*)d_in[14];
  const float* b_fc2   = (const float*)d_in[15];
  float* out = (float*)d_out;

  unsigned* flags1 = (unsigned*)d_ws;          // 32
  unsigned* flags2 = flags1 + 32;              // 32   (total 64 uints)
  float* p1 = (float*)d_ws + 64;               // 1536
  float* p2 = p1 + 1536;                       // 1536

  fused_kernel<<<32, 1024, 0, stream>>>(
      image, ques, conv1_w, conv1_b, bn1_g, bn1_b, conv2_w, conv2_b,
      bn2_g, bn2_b, w_rel, b_rel, w_fc1, b_fc1, w_fc2, b_fc2,
      out, flags1, flags2, p1, p2);
}

// Round 5
// 122.428 us; speedup vs baseline: 1.2374x; 1.2374x over previous
//
#include <hip/hip_runtime.h>
#include <math.h>

// R5: 256 blocks x 1024 threads = 32 n x 8 segs. Full-machine phase-thinning.
// R4 proved: HBM irrelevant (IC-resident replays equally slow), time ~ per-CU
// phase work. So split per-n work 8 ways: conv1 3 co/block, conv2 3 co/block
// (proven slot/LDS geometry kept), fc1 128-col slice/block. y1 exchanged via
// packed-u32 bf16 global buffer (device-scope relaxed stores, release-flag
// ordered), reassembled into the proven bordered pitch-40 LDS layout.
// 4 flag rounds: A=conv1 stats+y1g (256 flags, siblings polled first so
// assembly overlaps stragglers), B=BN2 stats (256), C=ssum (8 siblings),
// D=fc2 pairs (8 siblings). ws 0xAA-poisoned -> flags start != MAGIC.
// Fallback: if ws_size < ~1.7MB, launch the R3 kernel (192 blocks) unchanged.

#define MAGIC 0x13579BDFu
#define AGENT __HIP_MEMORY_SCOPE_AGENT
#define PITCH 40                 // ushorts per row (row 0 and col 0 are zero border)
#define NROWS 33
#define CHSZ (PITCH * NROWS)     // 1320 ushorts per channel plane (660 u32)
#define C_OUT 24

__device__ __forceinline__ float aload(const float* p) {
  return __hip_atomic_load(p, __ATOMIC_RELAXED, AGENT);
}
__device__ __forceinline__ void astore(float* p, float v) {
  __hip_atomic_store(p, v, __ATOMIC_RELAXED, AGENT);
}
__device__ __forceinline__ unsigned aloadu(const unsigned* p) {
  return __hip_atomic_load(p, __ATOMIC_RELAXED, AGENT);
}
__device__ __forceinline__ void astoreu(unsigned* p, unsigned v) {
  __hip_atomic_store(p, v, __ATOMIC_RELAXED, AGENT);
}
__device__ __forceinline__ void waitflag(const unsigned* f) {
  while (__hip_atomic_load(f, __ATOMIC_RELAXED, AGENT) != MAGIC)
    __builtin_amdgcn_s_sleep(1);
}

// ===================== R5 wide kernel (256 blocks) =====================
__global__ __launch_bounds__(1024) void fused_wide(
    const float* __restrict__ img, const float* __restrict__ ques,
    const float* __restrict__ c1w, const float* __restrict__ c1b,
    const float* __restrict__ g1,  const float* __restrict__ bt1,
    const float* __restrict__ c2w, const float* __restrict__ c2b,
    const float* __restrict__ g2,  const float* __restrict__ bt2,
    const float* __restrict__ w_rel, const float* __restrict__ b_rel,
    const float* __restrict__ w_fc1, const float* __restrict__ b_fc1,
    const float* __restrict__ w_fc2, const float* __restrict__ b_fc2,
    float* __restrict__ out,
    unsigned* __restrict__ flags1, unsigned* __restrict__ flags2,
    unsigned* __restrict__ flags3, unsigned* __restrict__ flags4,
    float* __restrict__ p1, float* __restrict__ p2,
    float* __restrict__ ssum, float* __restrict__ pairs,
    unsigned* __restrict__ y1g) {
  const int t = threadIdx.x;
  const int bid = blockIdx.x;
  const int lane = t & 63, wid = t >> 6;
  const int n = bid & 31;           // same-n siblings share an XCD (bid%8==n%8)
  const int seg = bid >> 5;         // 0..7; owns co {seg*3..+2}, fc1 cols seg*128..
  const int cobase = seg * 3;

  __shared__ __align__(16) unsigned short y1u[24 * CHSZ];   // 63.4 KB
  __align__(16) __shared__ float red[5120];
  __shared__ float s_a[C_OUT], s_b[C_OUT];
  __shared__ float a2[3], b2[3];
  __shared__ float chS[64], chS2[64];
  __shared__ float qpart[1024];
  __shared__ float qfull[128];
  __shared__ float s_s[26];
  __shared__ float s_coef[128];
  unsigned* lds32 = (unsigned*)y1u;

  // ---------------- phase 1: conv1, 1 px/thread, 3 co ----------------
  {
    const int oh = t >> 5, ow = t & 31;
    float win[27];
    #pragma unroll
    for (int ci = 0; ci < 3; ci++)
      #pragma unroll
      for (int kh = 0; kh < 3; kh++) {
        int ih = oh * 2 - 1 + kh;
        #pragma unroll
        for (int kw = 0; kw < 3; kw++) {
          int iw = ow * 2 - 1 + kw;
          win[ci * 9 + kh * 3 + kw] =
              (ih >= 0 && iw >= 0) ? img[(n * 3 + ci) * 4096 + ih * 64 + iw] : 0.f;
        }
      }
    unsigned x16[3]; float xb[3];
    #pragma unroll
    for (int j = 0; j < 3; j++) {
      const int co = cobase + j;
      float acc = c1b[co];
      #pragma unroll
      for (int q = 0; q < 27; q++) acc += win[q] * c1w[co * 27 + q];
      unsigned bits = __float_as_uint(acc);
      unsigned rr = (bits + 0x7FFFu + ((bits >> 16) & 1u)) >> 16;  // rne
      x16[j] = rr;
      xb[j] = __uint_as_float(rr << 16);
    }
    // y1g: cell c of a row holds (y[2c-1] lo | y[2c] hi); rows 0..31, cells 0..16
    const unsigned base = ((unsigned)(n * 24 + cobase) * 32 + oh) * 17;
    #pragma unroll
    for (int j = 0; j < 3; j++) {
      unsigned up = (unsigned)__shfl_down((int)x16[j], 1, 64);
      const unsigned rb = base + (unsigned)j * 544;   // 32*17 per channel
      if (ow & 1) {
        unsigned hi = (ow == 31) ? 0u : up;
        astoreu(&y1g[rb + ((unsigned)(ow + 1) >> 1)], x16[j] | (hi << 16));
      } else if (ow == 0) {
        astoreu(&y1g[rb], x16[j] << 16);   // (0 | y[0]<<16)
      }
    }
    // BN1 partial stats straight from registers
    #pragma unroll
    for (int j = 0; j < 3; j++) {
      float s = xb[j], s2 = xb[j] * xb[j];
      #pragma unroll
      for (int off = 32; off > 0; off >>= 1) {
        s += __shfl_down(s, off, 64);
        s2 += __shfl_down(s2, off, 64);
      }
      if (lane == 0) { chS[j * 16 + wid] = s; chS2[j * 16 + wid] = s2; }
    }
  }
  __syncthreads();
  if (t < 3) {
    float s = 0.f, s2 = 0.f;
    #pragma unroll
    for (int i = 0; i < 16; i++) { s += chS[t * 16 + i]; s2 += chS2[t * 16 + i]; }
    astore(&p1[(cobase + t) * 32 + n], s);
    astore(&p1[768 + (cobase + t) * 32 + n], s2);
  }
  __syncthreads();   // drain p1 + y1g stores of ALL threads before the flag
  if (t == 0)
    __hip_atomic_store(&flags1[bid], MAGIC, __ATOMIC_RELEASE, AGENT);

  // ---- L2 prefetch filler (own fc1 slice + w_rel + fc2/b slices) ----
  {
    float pf = 0.f;
    if (t < 512) pf += w_fc1[(t >> 2) * 1024 + seg * 128 + (t & 3) * 32];
    if (t < 720) pf += w_rel[t * 32];
    if (t < 8)   pf += w_fc2[seg * 256 + t * 32];
    if (t < 4)   pf += b_fc1[seg * 128 + t * 32];
    asm volatile("" :: "v"(pf));
  }

  // ---- wait siblings' y1g, assemble full y1 into LDS (overlaps stragglers) --
  if (t < 8 && t != seg) waitflag(&flags1[t * 32 + n]);
  __syncthreads();
  {
    const unsigned* yg = y1g + n * 13056;            // 24*32*17
    for (int i = t; i < 13056; i += 1024) {
      unsigned v = aloadu(yg + i);
      int co = i / 544;
      int rem = i - co * 544;
      int row = rem / 17;
      int c = rem - row * 17;
      lds32[co * 660 + (row + 1) * 20 + c] = v;      // border row 0 never read
    }
  }
  // ---- wait ALL for p1, finalize BN1 (all 24 ch) ----
  if (t < 256) waitflag(&flags1[t]);
  __syncthreads();
  if (t < 768) {
    int ch = t >> 5, j = t & 31;
    float s = aload(&p1[ch * 32 + j]);
    float s2 = aload(&p1[768 + ch * 32 + j]);
    #pragma unroll
    for (int off = 16; off > 0; off >>= 1) {
      s += __shfl_down(s, off, 32);
      s2 += __shfl_down(s2, off, 32);
    }
    if (j == 0) {
      float mu = s * (1.f / 32768.f);
      float var = s2 * (1.f / 32768.f) - mu * mu;
      float a = rsqrtf(var + 1e-5f) * g1[ch];
      s_a[ch] = a;
      s_b[ch] = bt1[ch] - mu * a;
    }
  }
  __syncthreads();

  // ---------------- phase 2: conv2, slot=6-ci split, 3 co partials ----------
  const int px = t & 255;
  const int slot = t >> 8;                  // 0..3, wave-uniform
  {
    const int o2h = px >> 4, o2w = px & 15;
    float accq[3] = {0.f, 0.f, 0.f};
    const int ci0 = slot * 6;
    #pragma unroll
    for (int cc = 0; cc < 6; cc++) {
      const int ci = ci0 + cc;
      const float a1 = s_a[ci], b1 = s_b[ci];
      const unsigned* chp = lds32 + ci * 660;
      #pragma unroll
      for (int kh = 0; kh < 3; kh++) {
        const int row = o2h * 2 + kh;
        const unsigned* pr = chp + row * 20;
        unsigned w0 = pr[o2w];
        unsigned w1 = pr[o2w + 1];
        float x0 = __uint_as_float(w0 << 16);
        float x1 = __uint_as_float(w0 & 0xffff0000u);
        float x2 = __uint_as_float(w1 << 16);
        x0 = fmaxf(fmaf(x0, a1, b1), 0.f);
        x1 = fmaxf(fmaf(x1, a1, b1), 0.f);
        x2 = fmaxf(fmaf(x2, a1, b1), 0.f);
        if (row == 0) { x0 = 0.f; x1 = 0.f; x2 = 0.f; }
        if (o2w == 0) x0 = 0.f;
        #pragma unroll
        for (int j = 0; j < 3; j++) {
          const float* wp = c2w + ((cobase + j) * C_OUT + ci) * 9 + kh * 3;
          accq[j] = fmaf(x0, wp[0], fmaf(x1, wp[1], fmaf(x2, wp[2], accq[j])));
        }
      }
    }
    #pragma unroll
    for (int j = 0; j < 3; j++) red[(slot * 256 + px) * 5 + j] = accq[j];
  }
  __syncthreads();
  float acc2 = 0.f;
  const int j2 = t >> 8;                    // 0..2 valid when t<768
  if (t < 768) {
    acc2 = c2b[cobase + j2];
    #pragma unroll
    for (int s = 0; s < 4; s++) acc2 += red[(s * 256 + px) * 5 + j2];
    float s = acc2, s2 = acc2 * acc2;
    #pragma unroll
    for (int off = 32; off > 0; off >>= 1) {
      s += __shfl_down(s, off, 64);
      s2 += __shfl_down(s2, off, 64);
    }
    if (lane == 0) { chS[j2 * 4 + (wid & 3)] = s; chS2[j2 * 4 + (wid & 3)] = s2; }
  }
  __syncthreads();
  if (t < 3) {
    float s = chS[t * 4] + chS[t * 4 + 1] + chS[t * 4 + 2] + chS[t * 4 + 3];
    float s2 = chS2[t * 4] + chS2[t * 4 + 1] + chS2[t * 4 + 2] + chS2[t * 4 + 3];
    astore(&p2[(cobase + t) * 32 + n], s);
    astore(&p2[768 + (cobase + t) * 32 + n], s2);
  }
  __syncthreads();
  if (t == 0)
    __hip_atomic_store(&flags2[bid], MAGIC, __ATOMIC_RELEASE, AGENT);

  // ---- qfull filler (redundant per block; fills round-B wait) ----
  {
    int m = t & 127, g = t >> 7;
    const float* qv = ques + n * 128;
    float q = 0.f;
    for (int k = g * 16; k < g * 16 + 16; k++)
      q += qv[k] * w_rel[(52 + k) * 128 + m];
    qpart[t] = q;
  }
  __syncthreads();
  if (t < 128) {
    float q = b_rel[t];
    #pragma unroll
    for (int g = 0; g < 8; g++) q += qpart[g * 128 + t];
    qfull[t] = 65536.f * q;
  }

  // ---- wait ALL for p2, finalize BN2 (own 3 ch only) ----
  if (t < 256) waitflag(&flags2[t]);
  __syncthreads();
  if (t < 96) {
    int j = t >> 5, l = t & 31;
    float s = aload(&p2[(cobase + j) * 32 + l]);
    float s2 = aload(&p2[768 + (cobase + j) * 32 + l]);
    #pragma unroll
    for (int off = 16; off > 0; off >>= 1) {
      s += __shfl_down(s, off, 32);
      s2 += __shfl_down(s2, off, 32);
    }
    if (l == 0) {
      float mu = s * (1.f / 8192.f);
      float var = s2 * (1.f / 8192.f) - mu * mu;
      float a = rsqrtf(var + 1e-5f) * g2[cobase + j];
      a2[j] = a;
      b2[j] = bt2[cobase + j] - mu * a;
    }
  }
  __syncthreads();

  // ---- relu(bn2) spatial sums for own 3 ch -> ssum ----
  if (t < 768) {
    float v = acc2 * a2[j2] + b2[j2];
    v = v > 0.f ? v : 0.f;
    #pragma unroll
    for (int off = 32; off > 0; off >>= 1) v += __shfl_down(v, off, 64);
    if (lane == 0) chS[j2 * 4 + (wid & 3)] = v;
  }
  __syncthreads();
  if (t < 3)
    astore(&ssum[n * C_OUT + cobase + t],
           chS[t * 4] + chS[t * 4 + 1] + chS[t * 4 + 2] + chS[t * 4 + 3]);
  __syncthreads();
  if (t == 0)
    __hip_atomic_store(&flags3[bid], MAGIC, __ATOMIC_RELEASE, AGENT);

  // ---------------- phase 3: all blocks, fc1 128-col slice ----------------
  if (t < 8 && t != seg) waitflag(&flags3[t * 32 + n]);
  __syncthreads();
  if (t < C_OUT) s_s[t] = aload(&ssum[n * C_OUT + t]);
  if (t == 24 || t == 25) {
    float cs = 0.f;
    for (int i = 0; i < 16; i++) cs += -1.f + 2.f * (float)i / 15.f;
    s_s[t] = 16.f * cs;
  }
  __syncthreads();
  {
    int col = t & 127, g = t >> 7;
    float p = 0.f;
    #pragma unroll
    for (int dd = 0; dd < 4; dd++) {
      int d = g + dd * 8;
      if (d < 26)
        p += s_s[d] * (w_rel[d * 128 + col] + w_rel[(26 + d) * 128 + col]);
    }
    qpart[t] = p;
  }
  __syncthreads();
  if (t < 128) {
    float sterm = 0.f;
    #pragma unroll
    for (int g = 0; g < 8; g++) sterm += qpart[g * 128 + t];
    s_coef[t] = qfull[t] + 256.f * sterm;
  }
  __syncthreads();

  // fc1 slice: 32 float4 col-groups x 32 m-segments of 4
  {
    const int gi = t & 31, ms = t >> 5;
    const float4* wp = (const float4*)w_fc1 + seg * 32 + gi;
    float4 a4 = make_float4(0.f, 0.f, 0.f, 0.f);
    #pragma unroll
    for (int k = 0; k < 4; k++) {
      int m = ms * 4 + k;
      float c = s_coef[m];
      float4 w = wp[m * 256];
      a4.x = fmaf(c, w.x, a4.x); a4.y = fmaf(c, w.y, a4.y);
      a4.z = fmaf(c, w.z, a4.z); a4.w = fmaf(c, w.w, a4.w);
    }
    red[(gi * 4 + 0) * 33 + ms] = a4.x;
    red[(gi * 4 + 1) * 33 + ms] = a4.y;
    red[(gi * 4 + 2) * 33 + ms] = a4.z;
    red[(gi * 4 + 3) * 33 + ms] = a4.w;
  }
  __syncthreads();
  float a0 = 0.f, a1v = 0.f;
  if (t < 128) {
    float h = b_fc1[seg * 128 + t];
    #pragma unroll
    for (int ms = 0; ms < 32; ms++) h += red[t * 33 + ms];
    h = h > 0.f ? h : 0.f;
    a0 = h * w_fc2[(seg * 128 + t) * 2];
    a1v = h * w_fc2[(seg * 128 + t) * 2 + 1];
  }
  {
    #pragma unroll
    for (int off = 32; off > 0; off >>= 1) {
      a0 += __shfl_down(a0, off, 64);
      a1v += __shfl_down(a1v, off, 64);
    }
    if (t < 128 && lane == 0) { chS[wid] = a0; chS2[wid] = a1v; }
  }
  __syncthreads();
  if (t == 0) {
    float b0 = chS[0] + chS[1], b1 = chS2[0] + chS2[1];
    if (seg != 0) {
      astore(&pairs[n * 16 + seg * 2 + 0], b0);
      astore(&pairs[n * 16 + seg * 2 + 1], b1);
      __hip_atomic_store(&flags4[bid], MAGIC, __ATOMIC_RELEASE, AGENT);
    } else {
      s_coef[0] = b0; s_coef[1] = b1;
    }
  }
  if (seg != 0) return;

  if (t >= 1 && t < 8) waitflag(&flags4[t * 32 + n]);
  __syncthreads();
  if (t == 0) {
    float b0 = s_coef[0], b1 = s_coef[1];
    #pragma unroll
    for (int i = 1; i < 8; i++) {
      b0 += aload(&pairs[n * 16 + i * 2 + 0]);
      b1 += aload(&pairs[n * 16 + i * 2 + 1]);
    }
    out[n * 2 + 0] = b0 + b_fc2[0];
    out[n * 2 + 1] = b1 + b_fc2[1];
  }
}

// ===================== R3 fallback kernel (192 blocks) =====================
__global__ __launch_bounds__(1024) void fused_kernel_r3(
    const float* __restrict__ img, const float* __restrict__ ques,
    const float* __restrict__ c1w, const float* __restrict__ c1b,
    const float* __restrict__ g1,  const float* __restrict__ bt1,
    const float* __restrict__ c2w, const float* __restrict__ c2b,
    const float* __restrict__ g2,  const float* __restrict__ bt2,
    const float* __restrict__ w_rel, const float* __restrict__ b_rel,
    const float* __restrict__ w_fc1, const float* __restrict__ b_fc1,
    const float* __restrict__ w_fc2, const float* __restrict__ b_fc2,
    float* __restrict__ out,
    unsigned* __restrict__ flags1, unsigned* __restrict__ flags2,
    unsigned* __restrict__ flags3, unsigned* __restrict__ flags4,
    float* __restrict__ p1, float* __restrict__ p2,
    float* __restrict__ ssum, float* __restrict__ pairs) {
  const int t = threadIdx.x;
  const int bid = blockIdx.x;
  const int lane = t & 63, wid = t >> 6;
  const int n = bid & 31;
  const int r = bid >> 5;
  const int g0 = r * 43 - (r == 5 ? 1 : 0);
  const int gcnt = (r < 4) ? 43 : 42;

  __shared__ unsigned short y1u[24 * CHSZ];
  __align__(16) __shared__ float red[5120];
  __shared__ float s_a[C_OUT], s_b[C_OUT];
  __shared__ float a2[4], b2[4];
  __shared__ float chS[16], chS2[16];
  __shared__ float qpart[1024];
  __shared__ float qfull[128];
  __shared__ float s_s[26];
  __shared__ float s_coef[128];

  if (t < 24 * PITCH) {
    int ch = t / PITCH;
    y1u[ch * CHSZ + (t - ch * PITCH)] = 0;
  }
  if (t < 768)
    y1u[(t >> 5) * CHSZ + ((t & 31) + 1) * PITCH] = 0;

  {
    int oh = t >> 5, ow = t & 31;
    float win[27];
    #pragma unroll
    for (int ci = 0; ci < 3; ci++)
      #pragma unroll
      for (int kh = 0; kh < 3; kh++) {
        int ih = oh * 2 - 1 + kh;
        #pragma unroll
        for (int kw = 0; kw < 3; kw++) {
          int iw = ow * 2 - 1 + kw;
          win[ci * 9 + kh * 3 + kw] =
              (ih >= 0 && iw >= 0) ? img[(n * 3 + ci) * 4096 + ih * 64 + iw] : 0.f;
        }
      }
    #pragma unroll
    for (int co = 0; co < C_OUT; co++) {
      float acc = c1b[co];
      #pragma unroll
      for (int q = 0; q < 27; q++) acc += win[q] * c1w[co * 27 + q];
      unsigned bits = __float_as_uint(acc);
      unsigned rr = (bits + 0x7FFFu + ((bits >> 16) & 1u)) >> 16;
      y1u[co * CHSZ + (oh + 1) * PITCH + (ow + 1)] = (unsigned short)rr;
    }
  }
  __syncthreads();

  if (r == 0) {
    if (t < 768) {
      int ch = t >> 5, l = t & 31;
      float s = 0.f, s2 = 0.f;
      #pragma unroll
      for (int i = 0; i < 32; i++) {
        float x = __uint_as_float(
            (unsigned)y1u[ch * CHSZ + (i + 1) * PITCH + (l + 1)] << 16);
        s += x; s2 += x * x;
      }
      #pragma unroll
      for (int off = 16; off > 0; off >>= 1) {
        s += __shfl_down(s, off, 32);
        s2 += __shfl_down(s2, off, 32);
      }
      if (l == 0) {
        astore(&p1[ch * 32 + n], s);
        astore(&p1[768 + ch * 32 + n], s2);
      }
    }
    __syncthreads();
    if (t == 0)
      __hip_atomic_store(&flags1[n], MAGIC, __ATOMIC_RELEASE, AGENT);
  }

  {
    float pf = 0.f;
    {
      int row = t >> 3, l = t & 7;
      int col = g0 * 4 + l * 32;
      col = col < 1024 ? col : 1023;
      pf += w_fc1[row * 1024 + col];
    }
    if (t < 720) pf += w_rel[t * 32];
    if (t < 64)  pf += w_fc2[t * 32];
    if (t < 32)  pf += b_fc1[t * 32];
    asm volatile("" :: "v"(pf));
  }

  if (t < 32) waitflag(&flags1[t]);
  __syncthreads();
  if (t < 768) {
    int ch = t >> 5, j = t & 31;
    float s = aload(&p1[ch * 32 + j]);
    float s2 = aload(&p1[768 + ch * 32 + j]);
    #pragma unroll
    for (int off = 16; off > 0; off >>= 1) {
      s += __shfl_down(s, off, 32);
      s2 += __shfl_down(s2, off, 32);
    }
    if (j == 0) {
      float mu = s * (1.f / 32768.f);
      float var = s2 * (1.f / 32768.f) - mu * mu;
      float a = rsqrtf(var + 1e-5f) * g1[ch];
      s_a[ch] = a;
      s_b[ch] = bt1[ch] - mu * a;
    }
  }
  __syncthreads();

  const int px = t & 255;
  const int slot = t >> 8;
  const int co2 = r * 4 + slot;
  float acc2;
  {
    const int o2h = px >> 4, o2w = px & 15;
    float accq[4] = {0.f, 0.f, 0.f, 0.f};
    const int ci0 = slot * 6;
    #pragma unroll
    for (int cc = 0; cc < 6; cc++) {
      const int ci = ci0 + cc;
      const float a1 = s_a[ci], b1 = s_b[ci];
      const unsigned* chp = (const unsigned*)(y1u + ci * CHSZ);
      #pragma unroll
      for (int kh = 0; kh < 3; kh++) {
        const int row = o2h * 2 + kh;
        const unsigned* pr = chp + row * (PITCH / 2);
        unsigned w0 = pr[o2w];
        unsigned w1 = pr[o2w + 1];
        float x0 = __uint_as_float(w0 << 16);
        float x1 = __uint_as_float(w0 & 0xffff0000u);
        float x2 = __uint_as_float(w1 << 16);
        x0 = fmaxf(fmaf(x0, a1, b1), 0.f);
        x1 = fmaxf(fmaf(x1, a1, b1), 0.f);
        x2 = fmaxf(fmaf(x2, a1, b1), 0.f);
        if (row == 0) { x0 = 0.f; x1 = 0.f; x2 = 0.f; }
        if (o2w == 0) x0 = 0.f;
        #pragma unroll
        for (int co = 0; co < 4; co++) {
          const float* wp = c2w + ((r * 4 + co) * C_OUT + ci) * 9 + kh * 3;
          accq[co] = fmaf(x0, wp[0], accq[co]);
          accq[co] = fmaf(x1, wp[1], accq[co]);
          accq[co] = fmaf(x2, wp[2], accq[co]);
        }
      }
    }
    #pragma unroll
    for (int q = 0; q < 4; q++) red[(slot * 256 + px) * 5 + q] = accq[q];
  }
  __syncthreads();
  {
    acc2 = c2b[co2];
    #pragma unroll
    for (int s = 0; s < 4; s++) acc2 += red[(s * 256 + px) * 5 + slot];
  }
  {
    float s = acc2, s2 = acc2 * acc2;
    #pragma unroll
    for (int off = 32; off > 0; off >>= 1) {
      s += __shfl_down(s, off, 64);
      s2 += __shfl_down(s2, off, 64);
    }
    if (lane == 0) { chS[slot * 4 + (wid & 3)] = s; chS2[slot * 4 + (wid & 3)] = s2; }
  }
  __syncthreads();
  if (t < 4) {
    float s = chS[t * 4] + chS[t * 4 + 1] + chS[t * 4 + 2] + chS[t * 4 + 3];
    float s2 = chS2[t * 4] + chS2[t * 4 + 1] + chS2[t * 4 + 2] + chS2[t * 4 + 3];
    astore(&p2[(r * 4 + t) * 32 + n], s);
    astore(&p2[768 + (r * 4 + t) * 32 + n], s2);
  }
  __syncthreads();
  if (t == 0)
    __hip_atomic_store(&flags2[bid], MAGIC, __ATOMIC_RELEASE, AGENT);

  {
    int m = t & 127, g = t >> 7;
    const float* qv = ques + n * 128;
    float q = 0.f;
    for (int k = g * 16; k < g * 16 + 16; k++)
      q += qv[k] * w_rel[(52 + k) * 128 + m];
    qpart[t] = q;
  }
  __syncthreads();
  if (t < 128) {
    float q = b_rel[t];
    #pragma unroll
    for (int g = 0; g < 8; g++) q += qpart[g * 128 + t];
    qfull[t] = 65536.f * q;
  }

  if (t < 32) waitflag(&flags2[r * 32 + t]);
  __syncthreads();
  if (t < 128) {
    int c4 = t >> 5, j = t & 31;
    float s = aload(&p2[(r * 4 + c4) * 32 + j]);
    float s2 = aload(&p2[768 + (r * 4 + c4) * 32 + j]);
    #pragma unroll
    for (int off = 16; off > 0; off >>= 1) {
      s += __shfl_down(s, off, 32);
      s2 += __shfl_down(s2, off, 32);
    }
    if (j == 0) {
      float mu = s * (1.f / 8192.f);
      float var = s2 * (1.f / 8192.f) - mu * mu;
      float a = rsqrtf(var + 1e-5f) * g2[r * 4 + c4];
      a2[c4] = a;
      b2[c4] = bt2[r * 4 + c4] - mu * a;
    }
  }
  __syncthreads();

  {
    float v = acc2 * a2[slot] + b2[slot];
    v = v > 0.f ? v : 0.f;
    #pragma unroll
    for (int off = 32; off > 0; off >>= 1) v += __shfl_down(v, off, 64);
    if (lane == 0) chS[slot * 4 + (wid & 3)] = v;
  }
  __syncthreads();
  if (t < 4)
    astore(&ssum[n * C_OUT + r * 4 + t],
           chS[t * 4] + chS[t * 4 + 1] + chS[t * 4 + 2] + chS[t * 4 + 3]);
  __syncthreads();
  if (t == 0)
    __hip_atomic_store(&flags3[bid], MAGIC, __ATOMIC_RELEASE, AGENT);

  if (t < 6 && t != r) waitflag(&flags3[t * 32 + n]);
  __syncthreads();
  if (t < C_OUT) s_s[t] = aload(&ssum[n * C_OUT + t]);
  if (t == 24 || t == 25) {
    float cs = 0.f;
    for (int i = 0; i < 16; i++) cs += -1.f + 2.f * (float)i / 15.f;
    s_s[t] = 16.f * cs;
  }
  __syncthreads();

  {
    int col = t & 127, g = t >> 7;
    float p = 0.f;
    #pragma unroll
    for (int dd = 0; dd < 4; dd++) {
      int d = g + dd * 8;
      if (d < 26)
        p += s_s[d] * (w_rel[d * 128 + col] + w_rel[(26 + d) * 128 + col]);
    }
    qpart[t] = p;
  }
  __syncthreads();
  if (t < 128) {
    float sterm = 0.f;
    #pragma unroll
    for (int g = 0; g < 8; g++) sterm += qpart[g * 128 + t];
    s_coef[t] = qfull[t] + 256.f * sterm;
  }
  __syncthreads();

  {
    const int gi = lane, mseg = wid;
    if (gi < gcnt) {
      const float4* wp = (const float4*)w_fc1 + (g0 + gi);
      float4 acc = make_float4(0.f, 0.f, 0.f, 0.f);
      #pragma unroll
      for (int k = 0; k < 8; k++) {
        int m = mseg * 8 + k;
        float c = s_coef[m];
        float4 w = wp[m * 256];
        acc.x += c * w.x; acc.y += c * w.y; acc.z += c * w.z; acc.w += c * w.w;
      }
      ((float4*)red)[mseg * 43 + gi] = acc;
    }
  }
  __syncthreads();
  float a0 = 0.f, a1 = 0.f;
  if (t < gcnt * 4) {
    const int gcol = g0 * 4 + t;
    float h = b_fc1[gcol];
    #pragma unroll
    for (int mseg = 0; mseg < 16; mseg++) h += red[mseg * 172 + t];
    h = h > 0.f ? h : 0.f;
    a0 = h * w_fc2[2 * gcol];
    a1 = h * w_fc2[2 * gcol + 1];
  }
  __syncthreads();
  {
    #pragma unroll
    for (int off = 32; off > 0; off >>= 1) {
      a0 += __shfl_down(a0, off, 64);
      a1 += __shfl_down(a1, off, 64);
    }
    if (lane == 0) { chS[wid] = a0; chS2[wid] = a1; }
  }
  __syncthreads();
  if (t == 0) {
    float b0 = 0.f, b1v = 0.f;
    #pragma unroll
    for (int i = 0; i < 16; i++) { b0 += chS[i]; b1v += chS2[i]; }
    if (r != 0) {
      astore(&pairs[n * 12 + r * 2 + 0], b0);
      astore(&pairs[n * 12 + r * 2 + 1], b1v);
      __hip_atomic_store(&flags4[bid], MAGIC, __ATOMIC_RELEASE, AGENT);
    } else {
      chS[0] = b0; chS2[0] = b1v;
    }
  }
  if (r != 0) return;

  if (t >= 1 && t < 6) waitflag(&flags4[t * 32 + n]);
  __syncthreads();
  if (t == 0) {
    float b0 = chS[0], b1v = chS2[0];
    #pragma unroll
    for (int i = 1; i < 6; i++) {
      b0 += aload(&pairs[n * 12 + i * 2 + 0]);
      b1v += aload(&pairs[n * 12 + i * 2 + 1]);
    }
    out[n * 2 + 0] = b0 + b_fc2[0];
    out[n * 2 + 1] = b1v + b_fc2[1];
  }
}

extern "C" void kernel_launch(void* const* d_in, const int* in_sizes, int n_in,
                              void* d_out, int out_size, void* d_ws, size_t ws_size,
                              hipStream_t stream) {
  const float* image   = (const float*)d_in[0];
  const float* ques    = (const float*)d_in[1];
  const float* conv1_w = (const float*)d_in[2];
  const float* conv1_b = (const float*)d_in[3];
  const float* bn1_g   = (const float*)d_in[4];
  const float* bn1_b   = (const float*)d_in[5];
  const float* conv2_w = (const float*)d_in[6];
  const float* conv2_b = (const float*)d_in[7];
  const float* bn2_g   = (const float*)d_in[8];
  const float* bn2_b   = (const float*)d_in[9];
  const float* w_rel   = (const float*)d_in[10];
  const float* b_rel   = (const float*)d_in[11];
  const float* w_fc1   = (const float*)d_in[12];
  const float* b_fc1   = (const float*)d_in[13];
  const float* w_fc2   = (const float*)d_in[14];
  const float* b_fc2   = (const float*)d_in[15];
  float* out = (float*)d_out;

  // wide layout: 4x256 flags | p1 1536 | p2 1536 | ssum 768 | pairs 512 | y1g 417792
  const size_t WIDE_WORDS = 1024 + 1536 + 1536 + 768 + 512 + 417792;
  if (ws_size >= WIDE_WORDS * 4) {
    unsigned* flags1 = (unsigned*)d_ws;
    unsigned* flags2 = flags1 + 256;
    unsigned* flags3 = flags2 + 256;
    unsigned* flags4 = flags3 + 256;
    float* p1    = (float*)(flags4 + 256);
    float* p2    = p1 + 1536;
    float* ssum  = p2 + 1536;
    float* pairs = ssum + 768;
    unsigned* y1g = (unsigned*)(pairs + 512);
    fused_wide<<<256, 1024, 0, stream>>>(
        image, ques, conv1_w, conv1_b, bn1_g, bn1_b, conv2_w, conv2_b,
        bn2_g, bn2_b, w_rel, b_rel, w_fc1, b_fc1, w_fc2, b_fc2,
        out, flags1, flags2, flags3, flags4, p1, p2, ssum, pairs, y1g);
  } else {
    unsigned* flags1 = (unsigned*)d_ws;
    unsigned* flags2 = flags1 + 32;
    unsigned* flags3 = flags2 + 192;
    unsigned* flags4 = flags3 + 192;
    float* p1    = (float*)d_ws + 608;
    float* p2    = p1 + 1536;
    float* ssum  = p2 + 1536;
    float* pairs = ssum + 768;
    fused_kernel_r3<<<192, 1024, 0, stream>>>(
        image, ques, conv1_w, conv1_b, bn1_g, bn1_b, conv2_w, conv2_b,
        bn2_g, bn2_b, w_rel, b_rel, w_fc1, b_fc1, w_fc2, b_fc2,
        out, flags1, flags2, flags3, flags4, p1, p2, ssum, pairs);
  }
}

// Round 6
// 108.671 us; speedup vs baseline: 1.3940x; 1.1266x over previous
//
#include <hip/hip_runtime.h>
#include <math.h>

// R6: 3-kernel stream-ordered chain — no flags, no polls, no atomics.
// R4/R5 established: time is pinned at ~43 µs across 32/192/256-block single-
// kernel variants while VALU/LDS/HBM/occupancy all moved -> the cost is the
// shared intra-kernel sync skeleton (flag rounds, IC-latency exchanges).
// Split at the two algorithmic barriers (BN1, BN2). Stream order provides
// release/acquire at each dispatch boundary; all cross-kernel data moves via
// plain stores/loads in ws:
//   K1 (256 blk): conv1 (3 co/block via seg), pack y1 bf16->y1g, BN1 partials
//       ->p1, L2/IC prefetch of tail weights.
//   K2 (256 blk): BN1 finalize (redundant), y1g->LDS (proven bordered pitch-40
//       layout), conv2 (proven slot-split), BN2 partials->p2, pre-BN conv2
//       output bf16->y2g.
//   K3 (32 blk, one per n): BN2 finalize, relu-bn2 spatial sums from y2g,
//       q-term + sterm, fused fc1 (coef = 65536*q + 256*sterm), fc2 -> out.
// Fallback: R3 single kernel if ws too small (needs ~2.08 MB).

#define MAGIC 0x13579BDFu
#define AGENT __HIP_MEMORY_SCOPE_AGENT
#define PITCH 40                 // ushorts per row (row 0 and col 0 are zero border)
#define NROWS 33
#define CHSZ (PITCH * NROWS)     // 1320 ushorts per channel plane (660 u32)
#define C_OUT 24

__device__ __forceinline__ float aload(const float* p) {
  return __hip_atomic_load(p, __ATOMIC_RELAXED, AGENT);
}
__device__ __forceinline__ void astore(float* p, float v) {
  __hip_atomic_store(p, v, __ATOMIC_RELAXED, AGENT);
}
__device__ __forceinline__ void waitflag(const unsigned* f) {
  while (__hip_atomic_load(f, __ATOMIC_RELAXED, AGENT) != MAGIC)
    __builtin_amdgcn_s_sleep(1);
}
__device__ __forceinline__ unsigned rne16(float f) {
  unsigned bits = __float_as_uint(f);
  return (bits + 0x7FFFu + ((bits >> 16) & 1u)) >> 16;
}

// ===================== K1: conv1 + BN1 partials (256 blocks) =====================
__global__ __launch_bounds__(1024) void k1_conv1(
    const float* __restrict__ img, const float* __restrict__ c1w,
    const float* __restrict__ c1b,
    const float* __restrict__ w_fc1, const float* __restrict__ w_rel,
    const float* __restrict__ w_fc2, const float* __restrict__ b_fc1,
    float* __restrict__ p1, unsigned* __restrict__ y1g) {
  const int t = threadIdx.x;
  const int bid = blockIdx.x;
  const int lane = t & 63, wid = t >> 6;
  const int n = bid & 31;
  const int seg = bid >> 5;          // 0..7, owns co seg*3..+2
  const int cobase = seg * 3;
  __shared__ float chS[64], chS2[64];

  const int oh = t >> 5, ow = t & 31;
  float win[27];
  #pragma unroll
  for (int ci = 0; ci < 3; ci++)
    #pragma unroll
    for (int kh = 0; kh < 3; kh++) {
      int ih = oh * 2 - 1 + kh;
      #pragma unroll
      for (int kw = 0; kw < 3; kw++) {
        int iw = ow * 2 - 1 + kw;
        win[ci * 9 + kh * 3 + kw] =
            (ih >= 0 && iw >= 0) ? img[(n * 3 + ci) * 4096 + ih * 64 + iw] : 0.f;
      }
    }
  unsigned x16[3]; float xb[3];
  #pragma unroll
  for (int j = 0; j < 3; j++) {
    const int co = cobase + j;
    float acc = c1b[co];
    #pragma unroll
    for (int q = 0; q < 27; q++) acc += win[q] * c1w[co * 27 + q];
    x16[j] = rne16(acc);
    xb[j] = __uint_as_float(x16[j] << 16);
  }
  // y1g: cell c of a row holds (y[2c-1] lo | y[2c] hi); rows 0..31, cells 0..16
  const unsigned base = ((unsigned)(n * 24 + cobase) * 32 + oh) * 17;
  #pragma unroll
  for (int j = 0; j < 3; j++) {
    unsigned up = (unsigned)__shfl_down((int)x16[j], 1, 64);
    const unsigned rb = base + (unsigned)j * 544;   // 32*17 per channel
    if (ow & 1) {
      unsigned hi = (ow == 31) ? 0u : up;
      y1g[rb + ((unsigned)(ow + 1) >> 1)] = x16[j] | (hi << 16);
    } else if (ow == 0) {
      y1g[rb] = x16[j] << 16;                        // (border0 | y[0]<<16)
    }
  }
  // BN1 partial stats straight from registers
  #pragma unroll
  for (int j = 0; j < 3; j++) {
    float s = xb[j], s2 = xb[j] * xb[j];
    #pragma unroll
    for (int off = 32; off > 0; off >>= 1) {
      s += __shfl_down(s, off, 64);
      s2 += __shfl_down(s2, off, 64);
    }
    if (lane == 0) { chS[j * 16 + wid] = s; chS2[j * 16 + wid] = s2; }
  }
  __syncthreads();
  if (t < 3) {
    float s = 0.f, s2 = 0.f;
    #pragma unroll
    for (int i = 0; i < 16; i++) { s += chS[t * 16 + i]; s2 += chS2[t * 16 + i]; }
    p1[(cobase + t) * 32 + n] = s;
    p1[768 + (cobase + t) * 32 + n] = s2;
  }
  // L2/IC prefetch of tail weights (own fc1 slice + w_rel + fc2/b slices)
  {
    float pf = 0.f;
    if (t < 512) pf += w_fc1[(t >> 2) * 1024 + seg * 128 + (t & 3) * 32];
    if (t < 720) pf += w_rel[t * 32];
    if (t < 8)   pf += w_fc2[seg * 256 + t * 32];
    if (t < 4)   pf += b_fc1[seg * 128 + t * 32];
    asm volatile("" :: "v"(pf));
  }
}

// ===================== K2: BN1 finalize + conv2 + BN2 partials (256) ==========
__global__ __launch_bounds__(1024) void k2_conv2(
    const float* __restrict__ g1, const float* __restrict__ bt1,
    const float* __restrict__ c2w, const float* __restrict__ c2b,
    const float* __restrict__ p1, const unsigned* __restrict__ y1g,
    float* __restrict__ p2, unsigned short* __restrict__ y2g) {
  const int t = threadIdx.x;
  const int bid = blockIdx.x;
  const int lane = t & 63, wid = t >> 6;
  const int n = bid & 31;
  const int seg = bid >> 5;
  const int cobase = seg * 3;

  __shared__ __align__(16) unsigned short y1u[24 * CHSZ];   // 63.4 KB
  __align__(16) __shared__ float red[5120];
  __shared__ float s_a[C_OUT], s_b[C_OUT];
  __shared__ float chS[64], chS2[64];
  unsigned* lds32 = (unsigned*)y1u;

  // y1g -> LDS assembly (plain loads; IC-resident from K1)
  {
    const unsigned* yg = y1g + n * 13056;            // 24*32*17
    for (int i = t; i < 13056; i += 1024) {
      unsigned v = yg[i];
      int co = i / 544;
      int rem = i - co * 544;
      int row = rem / 17;
      int c = rem - row * 17;
      lds32[co * 660 + (row + 1) * 20 + c] = v;      // border row 0 never used
    }
  }
  // BN1 finalize (redundant per block, all 24 ch)
  if (t < 768) {
    int ch = t >> 5, j = t & 31;
    float s = p1[ch * 32 + j];
    float s2 = p1[768 + ch * 32 + j];
    #pragma unroll
    for (int off = 16; off > 0; off >>= 1) {
      s += __shfl_down(s, off, 32);
      s2 += __shfl_down(s2, off, 32);
    }
    if (j == 0) {
      float mu = s * (1.f / 32768.f);
      float var = s2 * (1.f / 32768.f) - mu * mu;
      float a = rsqrtf(var + 1e-5f) * g1[ch];
      s_a[ch] = a;
      s_b[ch] = bt1[ch] - mu * a;
    }
  }
  __syncthreads();

  // conv2: slot = 6-ci split, partials for own 3 co
  const int px = t & 255;
  const int slot = t >> 8;
  {
    const int o2h = px >> 4, o2w = px & 15;
    float accq[3] = {0.f, 0.f, 0.f};
    const int ci0 = slot * 6;
    #pragma unroll
    for (int cc = 0; cc < 6; cc++) {
      const int ci = ci0 + cc;
      const float a1 = s_a[ci], b1 = s_b[ci];
      const unsigned* chp = lds32 + ci * 660;
      #pragma unroll
      for (int kh = 0; kh < 3; kh++) {
        const int row = o2h * 2 + kh;
        const unsigned* pr = chp + row * 20;
        unsigned w0 = pr[o2w];
        unsigned w1 = pr[o2w + 1];
        float x0 = __uint_as_float(w0 << 16);
        float x1 = __uint_as_float(w0 & 0xffff0000u);
        float x2 = __uint_as_float(w1 << 16);
        x0 = fmaxf(fmaf(x0, a1, b1), 0.f);
        x1 = fmaxf(fmaf(x1, a1, b1), 0.f);
        x2 = fmaxf(fmaf(x2, a1, b1), 0.f);
        if (row == 0) { x0 = 0.f; x1 = 0.f; x2 = 0.f; }
        if (o2w == 0) x0 = 0.f;
        #pragma unroll
        for (int j = 0; j < 3; j++) {
          const float* wp = c2w + ((cobase + j) * C_OUT + ci) * 9 + kh * 3;
          accq[j] = fmaf(x0, wp[0], fmaf(x1, wp[1], fmaf(x2, wp[2], accq[j])));
        }
      }
    }
    #pragma unroll
    for (int j = 0; j < 3; j++) red[(slot * 256 + px) * 5 + j] = accq[j];
  }
  __syncthreads();
  const int j2 = t >> 8;
  if (t < 768) {
    float acc2 = c2b[cobase + j2];
    #pragma unroll
    for (int s = 0; s < 4; s++) acc2 += red[(s * 256 + px) * 5 + j2];
    // pre-BN output to y2g (bf16, same precision precedent as y1)
    y2g[(n * 24 + cobase + j2) * 256 + px] = (unsigned short)rne16(acc2);
    float s = acc2, s2 = acc2 * acc2;
    #pragma unroll
    for (int off = 32; off > 0; off >>= 1) {
      s += __shfl_down(s, off, 64);
      s2 += __shfl_down(s2, off, 64);
    }
    if (lane == 0) { chS[j2 * 4 + (wid & 3)] = s; chS2[j2 * 4 + (wid & 3)] = s2; }
  }
  __syncthreads();
  if (t < 3) {
    float s = chS[t * 4] + chS[t * 4 + 1] + chS[t * 4 + 2] + chS[t * 4 + 3];
    float s2 = chS2[t * 4] + chS2[t * 4 + 1] + chS2[t * 4 + 2] + chS2[t * 4 + 3];
    p2[(cobase + t) * 32 + n] = s;
    p2[768 + (cobase + t) * 32 + n] = s2;
  }
}

// ===================== K3: BN2 finalize + tail (32 blocks) =====================
__global__ __launch_bounds__(1024) void k3_tail(
    const float* __restrict__ ques, const float* __restrict__ g2,
    const float* __restrict__ bt2,
    const float* __restrict__ w_rel, const float* __restrict__ b_rel,
    const float* __restrict__ w_fc1, const float* __restrict__ b_fc1,
    const float* __restrict__ w_fc2, const float* __restrict__ b_fc2,
    const float* __restrict__ p2, const unsigned* __restrict__ y2g32,
    float* __restrict__ out) {
  const int t = threadIdx.x;
  const int n = blockIdx.x;
  const int lane = t & 63, wid = t >> 6;

  __shared__ float s_a2[C_OUT], s_b2[C_OUT];
  __shared__ float s_s[26];
  __shared__ float qpart[1024], spart[1024];
  __shared__ float s_coef[128];
  __align__(16) __shared__ float red[4352];
  __shared__ float chS[16], chS2[16];

  // BN2 finalize (all 24 ch)
  if (t < 768) {
    int ch = t >> 5, j = t & 31;
    float s = p2[ch * 32 + j];
    float s2 = p2[768 + ch * 32 + j];
    #pragma unroll
    for (int off = 16; off > 0; off >>= 1) {
      s += __shfl_down(s, off, 32);
      s2 += __shfl_down(s2, off, 32);
    }
    if (j == 0) {
      float mu = s * (1.f / 8192.f);
      float var = s2 * (1.f / 8192.f) - mu * mu;
      float a = rsqrtf(var + 1e-5f) * g2[ch];
      s_a2[ch] = a;
      s_b2[ch] = bt2[ch] - mu * a;
    }
  }
  __syncthreads();

  // relu(bn2) spatial sums from y2g: ch = t>>5, lane l sums 8 px (one uint4)
  if (t < 768) {
    int ch = t >> 5, l = t & 31;
    const uint4 w4 = ((const uint4*)(y2g32 + (size_t)(n * 24 + ch) * 128))[l];
    const float a = s_a2[ch], b = s_b2[ch];
    float v = 0.f;
    const unsigned ws[4] = {w4.x, w4.y, w4.z, w4.w};
    #pragma unroll
    for (int q = 0; q < 4; q++) {
      float xlo = __uint_as_float(ws[q] << 16);
      float xhi = __uint_as_float(ws[q] & 0xffff0000u);
      float vlo = fmaf(xlo, a, b); vlo = vlo > 0.f ? vlo : 0.f;
      float vhi = fmaf(xhi, a, b); vhi = vhi > 0.f ? vhi : 0.f;
      v += vlo + vhi;
    }
    #pragma unroll
    for (int off = 16; off > 0; off >>= 1) v += __shfl_down(v, off, 32);
    if (l == 0) s_s[ch] = v;
  }
  if (t == 24 || t == 25) {
    float cs = 0.f;
    for (int i = 0; i < 16; i++) cs += -1.f + 2.f * (float)i / 15.f;
    s_s[t] = 16.f * cs;
  }
  __syncthreads();

  // q-term + sterm partials, combined pass (col = t&127, range by g = t>>7)
  {
    int col = t & 127, g = t >> 7;
    const float* qv = ques + n * 128;
    float q = 0.f;
    for (int k = g * 16; k < g * 16 + 16; k++)
      q += qv[k] * w_rel[(52 + k) * 128 + col];
    qpart[t] = q;
    float p = 0.f;
    #pragma unroll
    for (int dd = 0; dd < 4; dd++) {
      int d = g + dd * 8;
      if (d < 26)
        p += s_s[d] * (w_rel[d * 128 + col] + w_rel[(26 + d) * 128 + col]);
    }
    spart[t] = p;
  }
  __syncthreads();
  if (t < 128) {
    float q = b_rel[t], st = 0.f;
    #pragma unroll
    for (int g = 0; g < 8; g++) { q += qpart[g * 128 + t]; st += spart[g * 128 + t]; }
    s_coef[t] = 65536.f * q + 256.f * st;
  }
  __syncthreads();

  // fused fc1: coef @ w_fc1, float4 loads, mg-split
  {
    const int cg = t & 255, mg = t >> 8;          // cols 4cg..4cg+3, m mg*32..+31
    const float4* wp = (const float4*)(w_fc1) + mg * 32 * 256 + cg;
    float4 a4 = make_float4(0.f, 0.f, 0.f, 0.f);
    #pragma unroll 8
    for (int k = 0; k < 32; k++) {
      float c = s_coef[mg * 32 + k];
      float4 w = wp[k * 256];
      a4.x += c * w.x; a4.y += c * w.y; a4.z += c * w.z; a4.w += c * w.w;
    }
    red[cg * 17 + mg * 4 + 0] = a4.x;
    red[cg * 17 + mg * 4 + 1] = a4.y;
    red[cg * 17 + mg * 4 + 2] = a4.z;
    red[cg * 17 + mg * 4 + 3] = a4.w;
  }
  __syncthreads();
  float a0, a1v;
  {
    float h = b_fc1[t];
    #pragma unroll
    for (int mg = 0; mg < 4; mg++) h += red[(t >> 2) * 17 + mg * 4 + (t & 3)];
    h = h > 0.f ? h : 0.f;
    a0 = h * w_fc2[2 * t];
    a1v = h * w_fc2[2 * t + 1];
  }
  {
    #pragma unroll
    for (int off = 32; off > 0; off >>= 1) {
      a0 += __shfl_down(a0, off, 64);
      a1v += __shfl_down(a1v, off, 64);
    }
    if (lane == 0) { chS[wid] = a0; chS2[wid] = a1v; }
  }
  __syncthreads();
  if (t == 0) {
    float b0 = 0.f, b1 = 0.f;
    #pragma unroll
    for (int i = 0; i < 16; i++) { b0 += chS[i]; b1 += chS2[i]; }
    out[n * 2 + 0] = b0 + b_fc2[0];
    out[n * 2 + 1] = b1 + b_fc2[1];
  }
}

// ===================== R3 fallback kernel (192 blocks) =====================
__global__ __launch_bounds__(1024) void fused_kernel_r3(
    const float* __restrict__ img, const float* __restrict__ ques,
    const float* __restrict__ c1w, const float* __restrict__ c1b,
    const float* __restrict__ g1,  const float* __restrict__ bt1,
    const float* __restrict__ c2w, const float* __restrict__ c2b,
    const float* __restrict__ g2,  const float* __restrict__ bt2,
    const float* __restrict__ w_rel, const float* __restrict__ b_rel,
    const float* __restrict__ w_fc1, const float* __restrict__ b_fc1,
    const float* __restrict__ w_fc2, const float* __restrict__ b_fc2,
    float* __restrict__ out,
    unsigned* __restrict__ flags1, unsigned* __restrict__ flags2,
    unsigned* __restrict__ flags3, unsigned* __restrict__ flags4,
    float* __restrict__ p1, float* __restrict__ p2,
    float* __restrict__ ssum, float* __restrict__ pairs) {
  const int t = threadIdx.x;
  const int bid = blockIdx.x;
  const int lane = t & 63, wid = t >> 6;
  const int n = bid & 31;
  const int r = bid >> 5;
  const int g0 = r * 43 - (r == 5 ? 1 : 0);
  const int gcnt = (r < 4) ? 43 : 42;

  __shared__ unsigned short y1u[24 * CHSZ];
  __align__(16) __shared__ float red[5120];
  __shared__ float s_a[C_OUT], s_b[C_OUT];
  __shared__ float a2[4], b2[4];
  __shared__ float chS[16], chS2[16];
  __shared__ float qpart[1024];
  __shared__ float qfull[128];
  __shared__ float s_s[26];
  __shared__ float s_coef[128];

  if (t < 24 * PITCH) {
    int ch = t / PITCH;
    y1u[ch * CHSZ + (t - ch * PITCH)] = 0;
  }
  if (t < 768)
    y1u[(t >> 5) * CHSZ + ((t & 31) + 1) * PITCH] = 0;

  {
    int oh = t >> 5, ow = t & 31;
    float win[27];
    #pragma unroll
    for (int ci = 0; ci < 3; ci++)
      #pragma unroll
      for (int kh = 0; kh < 3; kh++) {
        int ih = oh * 2 - 1 + kh;
        #pragma unroll
        for (int kw = 0; kw < 3; kw++) {
          int iw = ow * 2 - 1 + kw;
          win[ci * 9 + kh * 3 + kw] =
              (ih >= 0 && iw >= 0) ? img[(n * 3 + ci) * 4096 + ih * 64 + iw] : 0.f;
        }
      }
    #pragma unroll
    for (int co = 0; co < C_OUT; co++) {
      float acc = c1b[co];
      #pragma unroll
      for (int q = 0; q < 27; q++) acc += win[q] * c1w[co * 27 + q];
      y1u[co * CHSZ + (oh + 1) * PITCH + (ow + 1)] = (unsigned short)rne16(acc);
    }
  }
  __syncthreads();

  if (r == 0) {
    if (t < 768) {
      int ch = t >> 5, l = t & 31;
      float s = 0.f, s2 = 0.f;
      #pragma unroll
      for (int i = 0; i < 32; i++) {
        float x = __uint_as_float(
            (unsigned)y1u[ch * CHSZ + (i + 1) * PITCH + (l + 1)] << 16);
        s += x; s2 += x * x;
      }
      #pragma unroll
      for (int off = 16; off > 0; off >>= 1) {
        s += __shfl_down(s, off, 32);
        s2 += __shfl_down(s2, off, 32);
      }
      if (l == 0) {
        astore(&p1[ch * 32 + n], s);
        astore(&p1[768 + ch * 32 + n], s2);
      }
    }
    __syncthreads();
    if (t == 0)
      __hip_atomic_store(&flags1[n], MAGIC, __ATOMIC_RELEASE, AGENT);
  }

  {
    float pf = 0.f;
    {
      int row = t >> 3, l = t & 7;
      int col = g0 * 4 + l * 32;
      col = col < 1024 ? col : 1023;
      pf += w_fc1[row * 1024 + col];
    }
    if (t < 720) pf += w_rel[t * 32];
    if (t < 64)  pf += w_fc2[t * 32];
    if (t < 32)  pf += b_fc1[t * 32];
    asm volatile("" :: "v"(pf));
  }

  if (t < 32) waitflag(&flags1[t]);
  __syncthreads();
  if (t < 768) {
    int ch = t >> 5, j = t & 31;
    float s = aload(&p1[ch * 32 + j]);
    float s2 = aload(&p1[768 + ch * 32 + j]);
    #pragma unroll
    for (int off = 16; off > 0; off >>= 1) {
      s += __shfl_down(s, off, 32);
      s2 += __shfl_down(s2, off, 32);
    }
    if (j == 0) {
      float mu = s * (1.f / 32768.f);
      float var = s2 * (1.f / 32768.f) - mu * mu;
      float a = rsqrtf(var + 1e-5f) * g1[ch];
      s_a[ch] = a;
      s_b[ch] = bt1[ch] - mu * a;
    }
  }
  __syncthreads();

  const int px = t & 255;
  const int slot = t >> 8;
  const int co2 = r * 4 + slot;
  float acc2;
  {
    const int o2h = px >> 4, o2w = px & 15;
    float accq[4] = {0.f, 0.f, 0.f, 0.f};
    const int ci0 = slot * 6;
    #pragma unroll
    for (int cc = 0; cc < 6; cc++) {
      const int ci = ci0 + cc;
      const float a1 = s_a[ci], b1 = s_b[ci];
      const unsigned* chp = (const unsigned*)(y1u + ci * CHSZ);
      #pragma unroll
      for (int kh = 0; kh < 3; kh++) {
        const int row = o2h * 2 + kh;
        const unsigned* pr = chp + row * (PITCH / 2);
        unsigned w0 = pr[o2w];
        unsigned w1 = pr[o2w + 1];
        float x0 = __uint_as_float(w0 << 16);
        float x1 = __uint_as_float(w0 & 0xffff0000u);
        float x2 = __uint_as_float(w1 << 16);
        x0 = fmaxf(fmaf(x0, a1, b1), 0.f);
        x1 = fmaxf(fmaf(x1, a1, b1), 0.f);
        x2 = fmaxf(fmaf(x2, a1, b1), 0.f);
        if (row == 0) { x0 = 0.f; x1 = 0.f; x2 = 0.f; }
        if (o2w == 0) x0 = 0.f;
        #pragma unroll
        for (int co = 0; co < 4; co++) {
          const float* wp = c2w + ((r * 4 + co) * C_OUT + ci) * 9 + kh * 3;
          accq[co] = fmaf(x0, wp[0], accq[co]);
          accq[co] = fmaf(x1, wp[1], accq[co]);
          accq[co] = fmaf(x2, wp[2], accq[co]);
        }
      }
    }
    #pragma unroll
    for (int q = 0; q < 4; q++) red[(slot * 256 + px) * 5 + q] = accq[q];
  }
  __syncthreads();
  {
    acc2 = c2b[co2];
    #pragma unroll
    for (int s = 0; s < 4; s++) acc2 += red[(s * 256 + px) * 5 + slot];
  }
  {
    float s = acc2, s2 = acc2 * acc2;
    #pragma unroll
    for (int off = 32; off > 0; off >>= 1) {
      s += __shfl_down(s, off, 64);
      s2 += __shfl_down(s2, off, 64);
    }
    if (lane == 0) { chS[slot * 4 + (wid & 3)] = s; chS2[slot * 4 + (wid & 3)] = s2; }
  }
  __syncthreads();
  if (t < 4) {
    float s = chS[t * 4] + chS[t * 4 + 1] + chS[t * 4 + 2] + chS[t * 4 + 3];
    float s2 = chS2[t * 4] + chS2[t * 4 + 1] + chS2[t * 4 + 2] + chS2[t * 4 + 3];
    astore(&p2[(r * 4 + t) * 32 + n], s);
    astore(&p2[768 + (r * 4 + t) * 32 + n], s2);
  }
  __syncthreads();
  if (t == 0)
    __hip_atomic_store(&flags2[bid], MAGIC, __ATOMIC_RELEASE, AGENT);

  {
    int m = t & 127, g = t >> 7;
    const float* qv = ques + n * 128;
    float q = 0.f;
    for (int k = g * 16; k < g * 16 + 16; k++)
      q += qv[k] * w_rel[(52 + k) * 128 + m];
    qpart[t] = q;
  }
  __syncthreads();
  if (t < 128) {
    float q = b_rel[t];
    #pragma unroll
    for (int g = 0; g < 8; g++) q += qpart[g * 128 + t];
    qfull[t] = 65536.f * q;
  }

  if (t < 32) waitflag(&flags2[r * 32 + t]);
  __syncthreads();
  if (t < 128) {
    int c4 = t >> 5, j = t & 31;
    float s = aload(&p2[(r * 4 + c4) * 32 + j]);
    float s2 = aload(&p2[768 + (r * 4 + c4) * 32 + j]);
    #pragma unroll
    for (int off = 16; off > 0; off >>= 1) {
      s += __shfl_down(s, off, 32);
      s2 += __shfl_down(s2, off, 32);
    }
    if (j == 0) {
      float mu = s * (1.f / 8192.f);
      float var = s2 * (1.f / 8192.f) - mu * mu;
      float a = rsqrtf(var + 1e-5f) * g2[r * 4 + c4];
      a2[c4] = a;
      b2[c4] = bt2[r * 4 + c4] - mu * a;
    }
  }
  __syncthreads();

  {
    float v = acc2 * a2[slot] + b2[slot];
    v = v > 0.f ? v : 0.f;
    #pragma unroll
    for (int off = 32; off > 0; off >>= 1) v += __shfl_down(v, off, 64);
    if (lane == 0) chS[slot * 4 + (wid & 3)] = v;
  }
  __syncthreads();
  if (t < 4)
    astore(&ssum[n * C_OUT + r * 4 + t],
           chS[t * 4] + chS[t * 4 + 1] + chS[t * 4 + 2] + chS[t * 4 + 3]);
  __syncthreads();
  if (t == 0)
    __hip_atomic_store(&flags3[bid], MAGIC, __ATOMIC_RELEASE, AGENT);

  if (t < 6 && t != r) waitflag(&flags3[t * 32 + n]);
  __syncthreads();
  if (t < C_OUT) s_s[t] = aload(&ssum[n * C_OUT + t]);
  if (t == 24 || t == 25) {
    float cs = 0.f;
    for (int i = 0; i < 16; i++) cs += -1.f + 2.f * (float)i / 15.f;
    s_s[t] = 16.f * cs;
  }
  __syncthreads();

  {
    int col = t & 127, g = t >> 7;
    float p = 0.f;
    #pragma unroll
    for (int dd = 0; dd < 4; dd++) {
      int d = g + dd * 8;
      if (d < 26)
        p += s_s[d] * (w_rel[d * 128 + col] + w_rel[(26 + d) * 128 + col]);
    }
    qpart[t] = p;
  }
  __syncthreads();
  if (t < 128) {
    float sterm = 0.f;
    #pragma unroll
    for (int g = 0; g < 8; g++) sterm += qpart[g * 128 + t];
    s_coef[t] = qfull[t] + 256.f * sterm;
  }
  __syncthreads();

  {
    const int gi = lane, mseg = wid;
    if (gi < gcnt) {
      const float4* wp = (const float4*)w_fc1 + (g0 + gi);
      float4 acc = make_float4(0.f, 0.f, 0.f, 0.f);
      #pragma unroll
      for (int k = 0; k < 8; k++) {
        int m = mseg * 8 + k;
        float c = s_coef[m];
        float4 w = wp[m * 256];
        acc.x += c * w.x; acc.y += c * w.y; acc.z += c * w.z; acc.w += c * w.w;
      }
      ((float4*)red)[mseg * 43 + gi] = acc;
    }
  }
  __syncthreads();
  float a0 = 0.f, a1 = 0.f;
  if (t < gcnt * 4) {
    const int gcol = g0 * 4 + t;
    float h = b_fc1[gcol];
    #pragma unroll
    for (int mseg = 0; mseg < 16; mseg++) h += red[mseg * 172 + t];
    h = h > 0.f ? h : 0.f;
    a0 = h * w_fc2[2 * gcol];
    a1 = h * w_fc2[2 * gcol + 1];
  }
  __syncthreads();
  {
    #pragma unroll
    for (int off = 32; off > 0; off >>= 1) {
      a0 += __shfl_down(a0, off, 64);
      a1 += __shfl_down(a1, off, 64);
    }
    if (lane == 0) { chS[wid] = a0; chS2[wid] = a1; }
  }
  __syncthreads();
  if (t == 0) {
    float b0 = 0.f, b1v = 0.f;
    #pragma unroll
    for (int i = 0; i < 16; i++) { b0 += chS[i]; b1v += chS2[i]; }
    if (r != 0) {
      astore(&pairs[n * 12 + r * 2 + 0], b0);
      astore(&pairs[n * 12 + r * 2 + 1], b1v);
      __hip_atomic_store(&flags4[bid], MAGIC, __ATOMIC_RELEASE, AGENT);
    } else {
      chS[0] = b0; chS2[0] = b1v;
    }
  }
  if (r != 0) return;

  if (t >= 1 && t < 6) waitflag(&flags4[t * 32 + n]);
  __syncthreads();
  if (t == 0) {
    float b0 = chS[0], b1v = chS2[0];
    #pragma unroll
    for (int i = 1; i < 6; i++) {
      b0 += aload(&pairs[n * 12 + i * 2 + 0]);
      b1v += aload(&pairs[n * 12 + i * 2 + 1]);
    }
    out[n * 2 + 0] = b0 + b_fc2[0];
    out[n * 2 + 1] = b1v + b_fc2[1];
  }
}

extern "C" void kernel_launch(void* const* d_in, const int* in_sizes, int n_in,
                              void* d_out, int out_size, void* d_ws, size_t ws_size,
                              hipStream_t stream) {
  const float* image   = (const float*)d_in[0];
  const float* ques    = (const float*)d_in[1];
  const float* conv1_w = (const float*)d_in[2];
  const float* conv1_b = (const float*)d_in[3];
  const float* bn1_g   = (const float*)d_in[4];
  const float* bn1_b   = (const float*)d_in[5];
  const float* conv2_w = (const float*)d_in[6];
  const float* conv2_b = (const float*)d_in[7];
  const float* bn2_g   = (const float*)d_in[8];
  const float* bn2_b   = (const float*)d_in[9];
  const float* w_rel   = (const float*)d_in[10];
  const float* b_rel   = (const float*)d_in[11];
  const float* w_fc1   = (const float*)d_in[12];
  const float* b_fc1   = (const float*)d_in[13];
  const float* w_fc2   = (const float*)d_in[14];
  const float* b_fc2   = (const float*)d_in[15];
  float* out = (float*)d_out;

  // 3-kernel layout: p1 1536 | p2 1536 | y1g 417792 u32 | y2g 98304 u32
  const size_t WORDS = 1536 + 1536 + 417792 + 98304;
  if (ws_size >= WORDS * 4) {
    float* p1 = (float*)d_ws;
    float* p2 = p1 + 1536;
    unsigned* y1g = (unsigned*)(p2 + 1536);
    unsigned* y2g = y1g + 417792;
    k1_conv1<<<256, 1024, 0, stream>>>(
        image, conv1_w, conv1_b, w_fc1, w_rel, w_fc2, b_fc1, p1, y1g);
    k2_conv2<<<256, 1024, 0, stream>>>(
        bn1_g, bn1_b, conv2_w, conv2_b, p1, y1g, p2, (unsigned short*)y2g);
    k3_tail<<<32, 1024, 0, stream>>>(
        ques, bn2_g, bn2_b, w_rel, b_rel, w_fc1, b_fc1, w_fc2, b_fc2,
        p2, y2g, out);
  } else {
    unsigned* flags1 = (unsigned*)d_ws;
    unsigned* flags2 = flags1 + 32;
    unsigned* flags3 = flags2 + 192;
    unsigned* flags4 = flags3 + 192;
    float* p1    = (float*)d_ws + 608;
    float* p2    = p1 + 1536;
    float* ssum  = p2 + 1536;
    float* pairs = ssum + 768;
    fused_kernel_r3<<<192, 1024, 0, stream>>>(
        image, ques, conv1_w, conv1_b, bn1_g, bn1_b, conv2_w, conv2_b,
        bn2_g, bn2_b, w_rel, b_rel, w_fc1, b_fc1, w_fc2, b_fc2,
        out, flags1, flags2, flags3, flags4, p1, p2, ssum, pairs);
  }
}

// Round 7
// 107.103 us; speedup vs baseline: 1.4144x; 1.0146x over previous
//
#include <hip/hip_runtime.h>
#include <math.h>

// R7: 3-kernel stream-ordered chain (R6 skeleton, proven: 43.7 -> ~28 µs of
// kernel time) + y1g stored by K1 in the EXACT LDS image layout so K2's
// re-assembly is 16 linear coalesced u32 moves with zero index math
// (was: 13-16 iters of i/544, rem/17 divisions + scattered writes).
// Layout: y1g[n*15840 + co*660 + (row+1)*20 + c], c=0..16; row 0, col 0 and
// cells 17..19 hold garbage -- harmless: row0/col0 are predicate-zeroed in
// conv2 and cells 17+ are never read.
//   K1 (256 blk = 32n x 8seg): conv1 (3 co/block), y1 bf16 -> y1g (LDS
//       layout), BN1 partials -> p1, L2/IC prefetch of tail weights.
//   K2 (256 blk): BN1 finalize (redundant), y1g -> LDS linear copy, conv2
//       (proven slot-split geometry), BN2 partials -> p2, pre-BN bf16 -> y2g.
//   K3 (32 blk, one per n): BN2 finalize, relu-bn2 spatial sums, q+sterm,
//       fused fc1 (coef = 65536*q + 256*sterm), fc2 -> out.
// Stream order provides release/acquire at each boundary; no flags/polls.
// Fallback: R3 single kernel if ws too small (needs ~2.43 MB).

#define MAGIC 0x13579BDFu
#define AGENT __HIP_MEMORY_SCOPE_AGENT
#define PITCH 40                 // ushorts per row (row 0 and col 0 are zero border)
#define NROWS 33
#define CHSZ (PITCH * NROWS)     // 1320 ushorts per channel plane (660 u32)
#define C_OUT 24
#define Y1N 15840                // u32 per n: 24 ch * 660

__device__ __forceinline__ float aload(const float* p) {
  return __hip_atomic_load(p, __ATOMIC_RELAXED, AGENT);
}
__device__ __forceinline__ void astore(float* p, float v) {
  __hip_atomic_store(p, v, __ATOMIC_RELAXED, AGENT);
}
__device__ __forceinline__ void waitflag(const unsigned* f) {
  while (__hip_atomic_load(f, __ATOMIC_RELAXED, AGENT) != MAGIC)
    __builtin_amdgcn_s_sleep(1);
}
__device__ __forceinline__ unsigned rne16(float f) {
  unsigned bits = __float_as_uint(f);
  return (bits + 0x7FFFu + ((bits >> 16) & 1u)) >> 16;
}

// ===================== K1: conv1 + BN1 partials (256 blocks) =====================
__global__ __launch_bounds__(1024) void k1_conv1(
    const float* __restrict__ img, const float* __restrict__ c1w,
    const float* __restrict__ c1b,
    const float* __restrict__ w_fc1, const float* __restrict__ w_rel,
    const float* __restrict__ w_fc2, const float* __restrict__ b_fc1,
    float* __restrict__ p1, unsigned* __restrict__ y1g) {
  const int t = threadIdx.x;
  const int bid = blockIdx.x;
  const int lane = t & 63, wid = t >> 6;
  const int n = bid & 31;
  const int seg = bid >> 5;          // 0..7, owns co seg*3..+2
  const int cobase = seg * 3;
  __shared__ float chS[64], chS2[64];

  const int oh = t >> 5, ow = t & 31;
  float win[27];
  #pragma unroll
  for (int ci = 0; ci < 3; ci++)
    #pragma unroll
    for (int kh = 0; kh < 3; kh++) {
      int ih = oh * 2 - 1 + kh;
      #pragma unroll
      for (int kw = 0; kw < 3; kw++) {
        int iw = ow * 2 - 1 + kw;
        win[ci * 9 + kh * 3 + kw] =
            (ih >= 0 && iw >= 0) ? img[(n * 3 + ci) * 4096 + ih * 64 + iw] : 0.f;
      }
    }
  unsigned x16[3]; float xb[3];
  #pragma unroll
  for (int j = 0; j < 3; j++) {
    const int co = cobase + j;
    float acc = c1b[co];
    #pragma unroll
    for (int q = 0; q < 27; q++) acc += win[q] * c1w[co * 27 + q];
    x16[j] = rne16(acc);
    xb[j] = __uint_as_float(x16[j] << 16);
  }
  // y1g in LDS-image layout: cell c holds (y[2c-1] lo | y[2c] hi), rows 1..32
  const unsigned base = (unsigned)(n * Y1N + cobase * 660 + (oh + 1) * 20);
  #pragma unroll
  for (int j = 0; j < 3; j++) {
    unsigned up = (unsigned)__shfl_down((int)x16[j], 1, 64);
    const unsigned rb = base + (unsigned)j * 660;
    if (ow & 1) {
      unsigned hi = (ow == 31) ? 0u : up;
      y1g[rb + ((unsigned)(ow + 1) >> 1)] = x16[j] | (hi << 16);
    } else if (ow == 0) {
      y1g[rb] = x16[j] << 16;                        // (border0 | y[0]<<16)
    }
  }
  // BN1 partial stats straight from registers
  #pragma unroll
  for (int j = 0; j < 3; j++) {
    float s = xb[j], s2 = xb[j] * xb[j];
    #pragma unroll
    for (int off = 32; off > 0; off >>= 1) {
      s += __shfl_down(s, off, 64);
      s2 += __shfl_down(s2, off, 64);
    }
    if (lane == 0) { chS[j * 16 + wid] = s; chS2[j * 16 + wid] = s2; }
  }
  __syncthreads();
  if (t < 3) {
    float s = 0.f, s2 = 0.f;
    #pragma unroll
    for (int i = 0; i < 16; i++) { s += chS[t * 16 + i]; s2 += chS2[t * 16 + i]; }
    p1[(cobase + t) * 32 + n] = s;
    p1[768 + (cobase + t) * 32 + n] = s2;
  }
  // L2/IC prefetch of tail weights (own fc1 slice + w_rel + fc2/b slices)
  {
    float pf = 0.f;
    if (t < 512) pf += w_fc1[(t >> 2) * 1024 + seg * 128 + (t & 3) * 32];
    if (t < 720) pf += w_rel[t * 32];
    if (t < 8)   pf += w_fc2[seg * 256 + t * 32];
    if (t < 4)   pf += b_fc1[seg * 128 + t * 32];
    asm volatile("" :: "v"(pf));
  }
}

// ===================== K2: BN1 finalize + conv2 + BN2 partials (256) ==========
__global__ __launch_bounds__(1024) void k2_conv2(
    const float* __restrict__ g1, const float* __restrict__ bt1,
    const float* __restrict__ c2w, const float* __restrict__ c2b,
    const float* __restrict__ p1, const unsigned* __restrict__ y1g,
    float* __restrict__ p2, unsigned short* __restrict__ y2g) {
  const int t = threadIdx.x;
  const int bid = blockIdx.x;
  const int lane = t & 63, wid = t >> 6;
  const int n = bid & 31;
  const int seg = bid >> 5;
  const int cobase = seg * 3;

  __shared__ __align__(16) unsigned short y1u[24 * CHSZ];   // 63.4 KB
  __align__(16) __shared__ float red[5120];
  __shared__ float s_a[C_OUT], s_b[C_OUT];
  __shared__ float chS[64], chS2[64];
  unsigned* lds32 = (unsigned*)y1u;

  // y1g -> LDS: linear, coalesced, zero index math (layouts match)
  {
    const unsigned* yg = y1g + n * Y1N;
    #pragma unroll
    for (int i = 0; i < 16; i++) {
      int idx = t + i * 1024;
      if (idx < Y1N) lds32[idx] = yg[idx];
    }
  }
  // BN1 finalize (redundant per block, all 24 ch)
  if (t < 768) {
    int ch = t >> 5, j = t & 31;
    float s = p1[ch * 32 + j];
    float s2 = p1[768 + ch * 32 + j];
    #pragma unroll
    for (int off = 16; off > 0; off >>= 1) {
      s += __shfl_down(s, off, 32);
      s2 += __shfl_down(s2, off, 32);
    }
    if (j == 0) {
      float mu = s * (1.f / 32768.f);
      float var = s2 * (1.f / 32768.f) - mu * mu;
      float a = rsqrtf(var + 1e-5f) * g1[ch];
      s_a[ch] = a;
      s_b[ch] = bt1[ch] - mu * a;
    }
  }
  __syncthreads();

  // conv2: slot = 6-ci split, partials for own 3 co
  const int px = t & 255;
  const int slot = t >> 8;
  {
    const int o2h = px >> 4, o2w = px & 15;
    float accq[3] = {0.f, 0.f, 0.f};
    const int ci0 = slot * 6;
    #pragma unroll
    for (int cc = 0; cc < 6; cc++) {
      const int ci = ci0 + cc;
      const float a1 = s_a[ci], b1 = s_b[ci];
      const unsigned* chp = lds32 + ci * 660;
      #pragma unroll
      for (int kh = 0; kh < 3; kh++) {
        const int row = o2h * 2 + kh;
        const unsigned* pr = chp + row * 20;
        unsigned w0 = pr[o2w];
        unsigned w1 = pr[o2w + 1];
        float x0 = __uint_as_float(w0 << 16);
        float x1 = __uint_as_float(w0 & 0xffff0000u);
        float x2 = __uint_as_float(w1 << 16);
        x0 = fmaxf(fmaf(x0, a1, b1), 0.f);
        x1 = fmaxf(fmaf(x1, a1, b1), 0.f);
        x2 = fmaxf(fmaf(x2, a1, b1), 0.f);
        if (row == 0) { x0 = 0.f; x1 = 0.f; x2 = 0.f; }
        if (o2w == 0) x0 = 0.f;
        #pragma unroll
        for (int j = 0; j < 3; j++) {
          const float* wp = c2w + ((cobase + j) * C_OUT + ci) * 9 + kh * 3;
          accq[j] = fmaf(x0, wp[0], fmaf(x1, wp[1], fmaf(x2, wp[2], accq[j])));
        }
      }
    }
    #pragma unroll
    for (int j = 0; j < 3; j++) red[(slot * 256 + px) * 5 + j] = accq[j];
  }
  __syncthreads();
  const int j2 = t >> 8;
  if (t < 768) {
    float acc2 = c2b[cobase + j2];
    #pragma unroll
    for (int s = 0; s < 4; s++) acc2 += red[(s * 256 + px) * 5 + j2];
    // pre-BN output to y2g (bf16, same precision precedent as y1)
    y2g[(n * 24 + cobase + j2) * 256 + px] = (unsigned short)rne16(acc2);
    float s = acc2, s2 = acc2 * acc2;
    #pragma unroll
    for (int off = 32; off > 0; off >>= 1) {
      s += __shfl_down(s, off, 64);
      s2 += __shfl_down(s2, off, 64);
    }
    if (lane == 0) { chS[j2 * 4 + (wid & 3)] = s; chS2[j2 * 4 + (wid & 3)] = s2; }
  }
  __syncthreads();
  if (t < 3) {
    float s = chS[t * 4] + chS[t * 4 + 1] + chS[t * 4 + 2] + chS[t * 4 + 3];
    float s2 = chS2[t * 4] + chS2[t * 4 + 1] + chS2[t * 4 + 2] + chS2[t * 4 + 3];
    p2[(cobase + t) * 32 + n] = s;
    p2[768 + (cobase + t) * 32 + n] = s2;
  }
}

// ===================== K3: BN2 finalize + tail (32 blocks) =====================
__global__ __launch_bounds__(1024) void k3_tail(
    const float* __restrict__ ques, const float* __restrict__ g2,
    const float* __restrict__ bt2,
    const float* __restrict__ w_rel, const float* __restrict__ b_rel,
    const float* __restrict__ w_fc1, const float* __restrict__ b_fc1,
    const float* __restrict__ w_fc2, const float* __restrict__ b_fc2,
    const float* __restrict__ p2, const unsigned* __restrict__ y2g32,
    float* __restrict__ out) {
  const int t = threadIdx.x;
  const int n = blockIdx.x;
  const int lane = t & 63, wid = t >> 6;

  __shared__ float s_a2[C_OUT], s_b2[C_OUT];
  __shared__ float s_s[26];
  __shared__ float qpart[1024], spart[1024];
  __shared__ float s_coef[128];
  __align__(16) __shared__ float red[4352];
  __shared__ float chS[16], chS2[16];

  // BN2 finalize (all 24 ch)
  if (t < 768) {
    int ch = t >> 5, j = t & 31;
    float s = p2[ch * 32 + j];
    float s2 = p2[768 + ch * 32 + j];
    #pragma unroll
    for (int off = 16; off > 0; off >>= 1) {
      s += __shfl_down(s, off, 32);
      s2 += __shfl_down(s2, off, 32);
    }
    if (j == 0) {
      float mu = s * (1.f / 8192.f);
      float var = s2 * (1.f / 8192.f) - mu * mu;
      float a = rsqrtf(var + 1e-5f) * g2[ch];
      s_a2[ch] = a;
      s_b2[ch] = bt2[ch] - mu * a;
    }
  }
  __syncthreads();

  // relu(bn2) spatial sums from y2g: ch = t>>5, lane l sums 8 px (one uint4)
  if (t < 768) {
    int ch = t >> 5, l = t & 31;
    const uint4 w4 = ((const uint4*)(y2g32 + (size_t)(n * 24 + ch) * 128))[l];
    const float a = s_a2[ch], b = s_b2[ch];
    float v = 0.f;
    const unsigned ws[4] = {w4.x, w4.y, w4.z, w4.w};
    #pragma unroll
    for (int q = 0; q < 4; q++) {
      float xlo = __uint_as_float(ws[q] << 16);
      float xhi = __uint_as_float(ws[q] & 0xffff0000u);
      float vlo = fmaf(xlo, a, b); vlo = vlo > 0.f ? vlo : 0.f;
      float vhi = fmaf(xhi, a, b); vhi = vhi > 0.f ? vhi : 0.f;
      v += vlo + vhi;
    }
    #pragma unroll
    for (int off = 16; off > 0; off >>= 1) v += __shfl_down(v, off, 32);
    if (l == 0) s_s[ch] = v;
  }
  if (t == 24 || t == 25) {
    float cs = 0.f;
    for (int i = 0; i < 16; i++) cs += -1.f + 2.f * (float)i / 15.f;
    s_s[t] = 16.f * cs;
  }
  __syncthreads();

  // q-term + sterm partials, combined pass (col = t&127, range by g = t>>7)
  {
    int col = t & 127, g = t >> 7;
    const float* qv = ques + n * 128;
    float q = 0.f;
    for (int k = g * 16; k < g * 16 + 16; k++)
      q += qv[k] * w_rel[(52 + k) * 128 + col];
    qpart[t] = q;
    float p = 0.f;
    #pragma unroll
    for (int dd = 0; dd < 4; dd++) {
      int d = g + dd * 8;
      if (d < 26)
        p += s_s[d] * (w_rel[d * 128 + col] + w_rel[(26 + d) * 128 + col]);
    }
    spart[t] = p;
  }
  __syncthreads();
  if (t < 128) {
    float q = b_rel[t], st = 0.f;
    #pragma unroll
    for (int g = 0; g < 8; g++) { q += qpart[g * 128 + t]; st += spart[g * 128 + t]; }
    s_coef[t] = 65536.f * q + 256.f * st;
  }
  __syncthreads();

  // fused fc1: coef @ w_fc1, float4 loads, mg-split
  {
    const int cg = t & 255, mg = t >> 8;          // cols 4cg..4cg+3, m mg*32..+31
    const float4* wp = (const float4*)(w_fc1) + mg * 32 * 256 + cg;
    float4 a4 = make_float4(0.f, 0.f, 0.f, 0.f);
    #pragma unroll 8
    for (int k = 0; k < 32; k++) {
      float c = s_coef[mg * 32 + k];
      float4 w = wp[k * 256];
      a4.x += c * w.x; a4.y += c * w.y; a4.z += c * w.z; a4.w += c * w.w;
    }
    red[cg * 17 + mg * 4 + 0] = a4.x;
    red[cg * 17 + mg * 4 + 1] = a4.y;
    red[cg * 17 + mg * 4 + 2] = a4.z;
    red[cg * 17 + mg * 4 + 3] = a4.w;
  }
  __syncthreads();
  float a0, a1v;
  {
    float h = b_fc1[t];
    #pragma unroll
    for (int mg = 0; mg < 4; mg++) h += red[(t >> 2) * 17 + mg * 4 + (t & 3)];
    h = h > 0.f ? h : 0.f;
    a0 = h * w_fc2[2 * t];
    a1v = h * w_fc2[2 * t + 1];
  }
  {
    #pragma unroll
    for (int off = 32; off > 0; off >>= 1) {
      a0 += __shfl_down(a0, off, 64);
      a1v += __shfl_down(a1v, off, 64);
    }
    if (lane == 0) { chS[wid] = a0; chS2[wid] = a1v; }
  }
  __syncthreads();
  if (t == 0) {
    float b0 = 0.f, b1 = 0.f;
    #pragma unroll
    for (int i = 0; i < 16; i++) { b0 += chS[i]; b1 += chS2[i]; }
    out[n * 2 + 0] = b0 + b_fc2[0];
    out[n * 2 + 1] = b1 + b_fc2[1];
  }
}

// ===================== R3 fallback kernel (192 blocks) =====================
__global__ __launch_bounds__(1024) void fused_kernel_r3(
    const float* __restrict__ img, const float* __restrict__ ques,
    const float* __restrict__ c1w, const float* __restrict__ c1b,
    const float* __restrict__ g1,  const float* __restrict__ bt1,
    const float* __restrict__ c2w, const float* __restrict__ c2b,
    const float* __restrict__ g2,  const float* __restrict__ bt2,
    const float* __restrict__ w_rel, const float* __restrict__ b_rel,
    const float* __restrict__ w_fc1, const float* __restrict__ b_fc1,
    const float* __restrict__ w_fc2, const float* __restrict__ b_fc2,
    float* __restrict__ out,
    unsigned* __restrict__ flags1, unsigned* __restrict__ flags2,
    unsigned* __restrict__ flags3, unsigned* __restrict__ flags4,
    float* __restrict__ p1, float* __restrict__ p2,
    float* __restrict__ ssum, float* __restrict__ pairs) {
  const int t = threadIdx.x;
  const int bid = blockIdx.x;
  const int lane = t & 63, wid = t >> 6;
  const int n = bid & 31;
  const int r = bid >> 5;
  const int g0 = r * 43 - (r == 5 ? 1 : 0);
  const int gcnt = (r < 4) ? 43 : 42;

  __shared__ unsigned short y1u[24 * CHSZ];
  __align__(16) __shared__ float red[5120];
  __shared__ float s_a[C_OUT], s_b[C_OUT];
  __shared__ float a2[4], b2[4];
  __shared__ float chS[16], chS2[16];
  __shared__ float qpart[1024];
  __shared__ float qfull[128];
  __shared__ float s_s[26];
  __shared__ float s_coef[128];

  if (t < 24 * PITCH) {
    int ch = t / PITCH;
    y1u[ch * CHSZ + (t - ch * PITCH)] = 0;
  }
  if (t < 768)
    y1u[(t >> 5) * CHSZ + ((t & 31) + 1) * PITCH] = 0;

  {
    int oh = t >> 5, ow = t & 31;
    float win[27];
    #pragma unroll
    for (int ci = 0; ci < 3; ci++)
      #pragma unroll
      for (int kh = 0; kh < 3; kh++) {
        int ih = oh * 2 - 1 + kh;
        #pragma unroll
        for (int kw = 0; kw < 3; kw++) {
          int iw = ow * 2 - 1 + kw;
          win[ci * 9 + kh * 3 + kw] =
              (ih >= 0 && iw >= 0) ? img[(n * 3 + ci) * 4096 + ih * 64 + iw] : 0.f;
        }
      }
    #pragma unroll
    for (int co = 0; co < C_OUT; co++) {
      float acc = c1b[co];
      #pragma unroll
      for (int q = 0; q < 27; q++) acc += win[q] * c1w[co * 27 + q];
      y1u[co * CHSZ + (oh + 1) * PITCH + (ow + 1)] = (unsigned short)rne16(acc);
    }
  }
  __syncthreads();

  if (r == 0) {
    if (t < 768) {
      int ch = t >> 5, l = t & 31;
      float s = 0.f, s2 = 0.f;
      #pragma unroll
      for (int i = 0; i < 32; i++) {
        float x = __uint_as_float(
            (unsigned)y1u[ch * CHSZ + (i + 1) * PITCH + (l + 1)] << 16);
        s += x; s2 += x * x;
      }
      #pragma unroll
      for (int off = 16; off > 0; off >>= 1) {
        s += __shfl_down(s, off, 32);
        s2 += __shfl_down(s2, off, 32);
      }
      if (l == 0) {
        astore(&p1[ch * 32 + n], s);
        astore(&p1[768 + ch * 32 + n], s2);
      }
    }
    __syncthreads();
    if (t == 0)
      __hip_atomic_store(&flags1[n], MAGIC, __ATOMIC_RELEASE, AGENT);
  }

  {
    float pf = 0.f;
    {
      int row = t >> 3, l = t & 7;
      int col = g0 * 4 + l * 32;
      col = col < 1024 ? col : 1023;
      pf += w_fc1[row * 1024 + col];
    }
    if (t < 720) pf += w_rel[t * 32];
    if (t < 64)  pf += w_fc2[t * 32];
    if (t < 32)  pf += b_fc1[t * 32];
    asm volatile("" :: "v"(pf));
  }

  if (t < 32) waitflag(&flags1[t]);
  __syncthreads();
  if (t < 768) {
    int ch = t >> 5, j = t & 31;
    float s = aload(&p1[ch * 32 + j]);
    float s2 = aload(&p1[768 + ch * 32 + j]);
    #pragma unroll
    for (int off = 16; off > 0; off >>= 1) {
      s += __shfl_down(s, off, 32);
      s2 += __shfl_down(s2, off, 32);
    }
    if (j == 0) {
      float mu = s * (1.f / 32768.f);
      float var = s2 * (1.f / 32768.f) - mu * mu;
      float a = rsqrtf(var + 1e-5f) * g1[ch];
      s_a[ch] = a;
      s_b[ch] = bt1[ch] - mu * a;
    }
  }
  __syncthreads();

  const int px = t & 255;
  const int slot = t >> 8;
  const int co2 = r * 4 + slot;
  float acc2;
  {
    const int o2h = px >> 4, o2w = px & 15;
    float accq[4] = {0.f, 0.f, 0.f, 0.f};
    const int ci0 = slot * 6;
    #pragma unroll
    for (int cc = 0; cc < 6; cc++) {
      const int ci = ci0 + cc;
      const float a1 = s_a[ci], b1 = s_b[ci];
      const unsigned* chp = (const unsigned*)(y1u + ci * CHSZ);
      #pragma unroll
      for (int kh = 0; kh < 3; kh++) {
        const int row = o2h * 2 + kh;
        const unsigned* pr = chp + row * (PITCH / 2);
        unsigned w0 = pr[o2w];
        unsigned w1 = pr[o2w + 1];
        float x0 = __uint_as_float(w0 << 16);
        float x1 = __uint_as_float(w0 & 0xffff0000u);
        float x2 = __uint_as_float(w1 << 16);
        x0 = fmaxf(fmaf(x0, a1, b1), 0.f);
        x1 = fmaxf(fmaf(x1, a1, b1), 0.f);
        x2 = fmaxf(fmaf(x2, a1, b1), 0.f);
        if (row == 0) { x0 = 0.f; x1 = 0.f; x2 = 0.f; }
        if (o2w == 0) x0 = 0.f;
        #pragma unroll
        for (int co = 0; co < 4; co++) {
          const float* wp = c2w + ((r * 4 + co) * C_OUT + ci) * 9 + kh * 3;
          accq[co] = fmaf(x0, wp[0], accq[co]);
          accq[co] = fmaf(x1, wp[1], accq[co]);
          accq[co] = fmaf(x2, wp[2], accq[co]);
        }
      }
    }
    #pragma unroll
    for (int q = 0; q < 4; q++) red[(slot * 256 + px) * 5 + q] = accq[q];
  }
  __syncthreads();
  {
    acc2 = c2b[co2];
    #pragma unroll
    for (int s = 0; s < 4; s++) acc2 += red[(s * 256 + px) * 5 + slot];
  }
  {
    float s = acc2, s2 = acc2 * acc2;
    #pragma unroll
    for (int off = 32; off > 0; off >>= 1) {
      s += __shfl_down(s, off, 64);
      s2 += __shfl_down(s2, off, 64);
    }
    if (lane == 0) { chS[slot * 4 + (wid & 3)] = s; chS2[slot * 4 + (wid & 3)] = s2; }
  }
  __syncthreads();
  if (t < 4) {
    float s = chS[t * 4] + chS[t * 4 + 1] + chS[t * 4 + 2] + chS[t * 4 + 3];
    float s2 = chS2[t * 4] + chS2[t * 4 + 1] + chS2[t * 4 + 2] + chS2[t * 4 + 3];
    astore(&p2[(r * 4 + t) * 32 + n], s);
    astore(&p2[768 + (r * 4 + t) * 32 + n], s2);
  }
  __syncthreads();
  if (t == 0)
    __hip_atomic_store(&flags2[bid], MAGIC, __ATOMIC_RELEASE, AGENT);

  {
    int m = t & 127, g = t >> 7;
    const float* qv = ques + n * 128;
    float q = 0.f;
    for (int k = g * 16; k < g * 16 + 16; k++)
      q += qv[k] * w_rel[(52 + k) * 128 + m];
    qpart[t] = q;
  }
  __syncthreads();
  if (t < 128) {
    float q = b_rel[t];
    #pragma unroll
    for (int g = 0; g < 8; g++) q += qpart[g * 128 + t];
    qfull[t] = 65536.f * q;
  }

  if (t < 32) waitflag(&flags2[r * 32 + t]);
  __syncthreads();
  if (t < 128) {
    int c4 = t >> 5, j = t & 31;
    float s = aload(&p2[(r * 4 + c4) * 32 + j]);
    float s2 = aload(&p2[768 + (r * 4 + c4) * 32 + j]);
    #pragma unroll
    for (int off = 16; off > 0; off >>= 1) {
      s += __shfl_down(s, off, 32);
      s2 += __shfl_down(s2, off, 32);
    }
    if (j == 0) {
      float mu = s * (1.f / 8192.f);
      float var = s2 * (1.f / 8192.f) - mu * mu;
      float a = rsqrtf(var + 1e-5f) * g2[r * 4 + c4];
      a2[c4] = a;
      b2[c4] = bt2[r * 4 + c4] - mu * a;
    }
  }
  __syncthreads();

  {
    float v = acc2 * a2[slot] + b2[slot];
    v = v > 0.f ? v : 0.f;
    #pragma unroll
    for (int off = 32; off > 0; off >>= 1) v += __shfl_down(v, off, 64);
    if (lane == 0) chS[slot * 4 + (wid & 3)] = v;
  }
  __syncthreads();
  if (t < 4)
    astore(&ssum[n * C_OUT + r * 4 + t],
           chS[t * 4] + chS[t * 4 + 1] + chS[t * 4 + 2] + chS[t * 4 + 3]);
  __syncthreads();
  if (t == 0)
    __hip_atomic_store(&flags3[bid], MAGIC, __ATOMIC_RELEASE, AGENT);

  if (t < 6 && t != r) waitflag(&flags3[t * 32 + n]);
  __syncthreads();
  if (t < C_OUT) s_s[t] = aload(&ssum[n * C_OUT + t]);
  if (t == 24 || t == 25) {
    float cs = 0.f;
    for (int i = 0; i < 16; i++) cs += -1.f + 2.f * (float)i / 15.f;
    s_s[t] = 16.f * cs;
  }
  __syncthreads();

  {
    int col = t & 127, g = t >> 7;
    float p = 0.f;
    #pragma unroll
    for (int dd = 0; dd < 4; dd++) {
      int d = g + dd * 8;
      if (d < 26)
        p += s_s[d] * (w_rel[d * 128 + col] + w_rel[(26 + d) * 128 + col]);
    }
    qpart[t] = p;
  }
  __syncthreads();
  if (t < 128) {
    float sterm = 0.f;
    #pragma unroll
    for (int g = 0; g < 8; g++) sterm += qpart[g * 128 + t];
    s_coef[t] = qfull[t] + 256.f * sterm;
  }
  __syncthreads();

  {
    const int gi = lane, mseg = wid;
    if (gi < gcnt) {
      const float4* wp = (const float4*)w_fc1 + (g0 + gi);
      float4 acc = make_float4(0.f, 0.f, 0.f, 0.f);
      #pragma unroll
      for (int k = 0; k < 8; k++) {
        int m = mseg * 8 + k;
        float c = s_coef[m];
        float4 w = wp[m * 256];
        acc.x += c * w.x; acc.y += c * w.y; acc.z += c * w.z; acc.w += c * w.w;
      }
      ((float4*)red)[mseg * 43 + gi] = acc;
    }
  }
  __syncthreads();
  float a0 = 0.f, a1 = 0.f;
  if (t < gcnt * 4) {
    const int gcol = g0 * 4 + t;
    float h = b_fc1[gcol];
    #pragma unroll
    for (int mseg = 0; mseg < 16; mseg++) h += red[mseg * 172 + t];
    h = h > 0.f ? h : 0.f;
    a0 = h * w_fc2[2 * gcol];
    a1 = h * w_fc2[2 * gcol + 1];
  }
  __syncthreads();
  {
    #pragma unroll
    for (int off = 32; off > 0; off >>= 1) {
      a0 += __shfl_down(a0, off, 64);
      a1 += __shfl_down(a1, off, 64);
    }
    if (lane == 0) { chS[wid] = a0; chS2[wid] = a1; }
  }
  __syncthreads();
  if (t == 0) {
    float b0 = 0.f, b1v = 0.f;
    #pragma unroll
    for (int i = 0; i < 16; i++) { b0 += chS[i]; b1v += chS2[i]; }
    if (r != 0) {
      astore(&pairs[n * 12 + r * 2 + 0], b0);
      astore(&pairs[n * 12 + r * 2 + 1], b1v);
      __hip_atomic_store(&flags4[bid], MAGIC, __ATOMIC_RELEASE, AGENT);
    } else {
      chS[0] = b0; chS2[0] = b1v;
    }
  }
  if (r != 0) return;

  if (t >= 1 && t < 6) waitflag(&flags4[t * 32 + n]);
  __syncthreads();
  if (t == 0) {
    float b0 = chS[0], b1v = chS2[0];
    #pragma unroll
    for (int i = 1; i < 6; i++) {
      b0 += aload(&pairs[n * 12 + i * 2 + 0]);
      b1v += aload(&pairs[n * 12 + i * 2 + 1]);
    }
    out[n * 2 + 0] = b0 + b_fc2[0];
    out[n * 2 + 1] = b1v + b_fc2[1];
  }
}

extern "C" void kernel_launch(void* const* d_in, const int* in_sizes, int n_in,
                              void* d_out, int out_size, void* d_ws, size_t ws_size,
                              hipStream_t stream) {
  const float* image   = (const float*)d_in[0];
  const float* ques    = (const float*)d_in[1];
  const float* conv1_w = (const float*)d_in[2];
  const float* conv1_b = (const float*)d_in[3];
  const float* bn1_g   = (const float*)d_in[4];
  const float* bn1_b   = (const float*)d_in[5];
  const float* conv2_w = (const float*)d_in[6];
  const float* conv2_b = (const float*)d_in[7];
  const float* bn2_g   = (const float*)d_in[8];
  const float* bn2_b   = (const float*)d_in[9];
  const float* w_rel   = (const float*)d_in[10];
  const float* b_rel   = (const float*)d_in[11];
  const float* w_fc1   = (const float*)d_in[12];
  const float* b_fc1   = (const float*)d_in[13];
  const float* w_fc2   = (const float*)d_in[14];
  const float* b_fc2   = (const float*)d_in[15];
  float* out = (float*)d_out;

  // 3-kernel layout: p1 1536 | p2 1536 | y1g 506880 u32 | y2g 98304 u32
  const size_t WORDS = 1536 + 1536 + (size_t)32 * Y1N + 98304;
  if (ws_size >= WORDS * 4) {
    float* p1 = (float*)d_ws;
    float* p2 = p1 + 1536;
    unsigned* y1g = (unsigned*)(p2 + 1536);
    unsigned* y2g = y1g + (size_t)32 * Y1N;
    k1_conv1<<<256, 1024, 0, stream>>>(
        image, conv1_w, conv1_b, w_fc1, w_rel, w_fc2, b_fc1, p1, y1g);
    k2_conv2<<<256, 1024, 0, stream>>>(
        bn1_g, bn1_b, conv2_w, conv2_b, p1, y1g, p2, (unsigned short*)y2g);
    k3_tail<<<32, 1024, 0, stream>>>(
        ques, bn2_g, bn2_b, w_rel, b_rel, w_fc1, b_fc1, w_fc2, b_fc2,
        p2, y2g, out);
  } else {
    unsigned* flags1 = (unsigned*)d_ws;
    unsigned* flags2 = flags1 + 32;
    unsigned* flags3 = flags2 + 192;
    unsigned* flags4 = flags3 + 192;
    float* p1    = (float*)d_ws + 608;
    float* p2    = p1 + 1536;
    float* ssum  = p2 + 1536;
    float* pairs = ssum + 768;
    fused_kernel_r3<<<192, 1024, 0, stream>>>(
        image, ques, conv1_w, conv1_b, bn1_g, bn1_b, conv2_w, conv2_b,
        bn2_g, bn2_b, w_rel, b_rel, w_fc1, b_fc1, w_fc2, b_fc2,
        out, flags1, flags2, flags3, flags4, p1, p2, ssum, pairs);
  }
}